// Round 12
// baseline (2764.924 us; speedup 1.0000x reference)
//
#include <hip/hip_runtime.h>
#include <hip/hip_bf16.h>

#define EPS_BN 1e-5f
constexpr int BB = 16, NN = 2048, SS1 = 512, SS2 = 256, KNb = 32;

typedef short bf16x8 __attribute__((ext_vector_type(8)));
typedef float f32x4 __attribute__((ext_vector_type(4)));

__device__ inline float bflo(unsigned u) { return __uint_as_float(u << 16); }
__device__ inline float bfhi(unsigned u) { return __uint_as_float(u & 0xffff0000u); }
__device__ inline unsigned short f2bf_bits(float v) {
  __hip_bfloat16 h = __float2bfloat16(v);
  return *reinterpret_cast<unsigned short*>(&h);
}
__device__ inline unsigned fmono(float v) {
  int b = __float_as_int(v);
  return (unsigned)(b ^ ((b >> 31) | 0x80000000));
}
__device__ inline unsigned bn2(unsigned u, float s0, float h0, float s1, float h1) {
  float v0 = fmaxf(bflo(u) * s0 + h0, 0.f);
  float v1 = fmaxf(bfhi(u) * s1 + h1, 0.f);
  return (unsigned)f2bf_bits(v0) | ((unsigned)f2bf_bits(v1) << 16);
}

// ---- DPP compound-key wave64 reduction (round-6 lesson: DPP+readlane at full exec)
template <int CTRL>
__device__ inline void dpp_step_min(unsigned& hi, unsigned& lo) {
  unsigned hs = (unsigned)__builtin_amdgcn_update_dpp((int)hi, (int)hi, CTRL, 0xF, 0xF, false);
  unsigned ls = (unsigned)__builtin_amdgcn_update_dpp((int)lo, (int)lo, CTRL, 0xF, 0xF, false);
  bool take = (hs < hi) || (hs == hi && ls < lo);
  hi = take ? hs : hi; lo = take ? ls : lo;
}
template <int CTRL>
__device__ inline void dpp_step_maxv_minidx(unsigned& hi, unsigned& lo) {
  unsigned hs = (unsigned)__builtin_amdgcn_update_dpp((int)hi, (int)hi, CTRL, 0xF, 0xF, false);
  unsigned ls = (unsigned)__builtin_amdgcn_update_dpp((int)lo, (int)lo, CTRL, 0xF, 0xF, false);
  bool take = (hs > hi) || (hs == hi && ls < lo);
  hi = take ? hs : hi; lo = take ? ls : lo;
}
__device__ inline void dpp_chain_min(unsigned& hi, unsigned& lo) {
  dpp_step_min<0x111>(hi, lo); dpp_step_min<0x112>(hi, lo);
  dpp_step_min<0x114>(hi, lo); dpp_step_min<0x118>(hi, lo);
  dpp_step_min<0x142>(hi, lo); dpp_step_min<0x143>(hi, lo);
}
__device__ inline void dpp_chain_maxv_minidx(unsigned& hi, unsigned& lo) {
  dpp_step_maxv_minidx<0x111>(hi, lo); dpp_step_maxv_minidx<0x112>(hi, lo);
  dpp_step_maxv_minidx<0x114>(hi, lo); dpp_step_maxv_minidx<0x118>(hi, lo);
  dpp_step_maxv_minidx<0x142>(hi, lo); dpp_step_maxv_minidx<0x143>(hi, lo);
}
__device__ inline int dpp_reduce_min_idx(unsigned hi, unsigned lo) {
  dpp_chain_min(hi, lo);
  return __builtin_amdgcn_readlane((int)lo, 63);
}

// ---- "last block finalizes" tail: replaces the standalone k_finalize launch.
// Producers atomicAdd rsum/rsq (device-scope), fence, bump counter; the last
// block computes BN scale/shift. Consumers are in LATER kernels (stream order).
__device__ inline void fin_tail(unsigned* cnt, unsigned total,
                                const double* rsum, const double* rsq, int O, int rows,
                                const float* gamma, const float* beta,
                                float* scale, float* shift) {
  __threadfence();
  __shared__ unsigned done_;
  if (threadIdx.x == 0) done_ = atomicAdd(cnt, 1u);
  __syncthreads();
  if (done_ == total - 1) {
    for (int o = threadIdx.x; o < O; o += blockDim.x) {
      double s = 0, s2 = 0;
      for (int r = 0; r < 64; r++) { s += rsum[(size_t)r * O + o]; s2 += rsq[(size_t)r * O + o]; }
      double mean = s / rows;
      double var = s2 / rows - mean * mean;
      float sc = gamma[o] * rsqrtf((float)var + EPS_BN);
      scale[o] = sc; shift[o] = beta[o] - (float)mean * sc;
    }
  }
}

// ================================================================ MEGA1
__global__ __launch_bounds__(256, 1) void k_mega1(
    const float* __restrict__ x, const float* __restrict__ emb_w1,
    float* __restrict__ fA, double* __restrict__ rsE1, double* __restrict__ rqE1,
    int* __restrict__ fps1, float* __restrict__ nx1,
    int* __restrict__ fps2, float* __restrict__ nx2,
    const float* __restrict__ w11f, __hip_bfloat16* __restrict__ wb11,
    const float* __restrict__ w12f, __hip_bfloat16* __restrict__ wb12,
    const float* __restrict__ w21f, __hip_bfloat16* __restrict__ wb21,
    const float* __restrict__ w22f, __hip_bfloat16* __restrict__ wb22,
    unsigned* __restrict__ cntE1, const float* __restrict__ emb_g1,
    const float* __restrict__ emb_b1, float* __restrict__ sc_e1, float* __restrict__ sh_e1) {
  int blk = blockIdx.x;
  int t = threadIdx.x;
  if (blk < BB) {
    constexpr int PPL = NN / 256;   // 8
    int b = blk; int w = t >> 6; int lane = t & 63;
    __shared__ float4 sxyz[NN];
    __shared__ float4 c4[SS1];
    __shared__ unsigned combH[2][4], combL[2][4];
    float px[PPL], py[PPL], pz[PPL], ds[PPL];
#pragma unroll
    for (int r = 0; r < PPL; r++) {
      int i = r * 256 + t;
      float xx = x[(size_t)(b * 3 + 0) * NN + i];
      float yy = x[(size_t)(b * 3 + 1) * NN + i];
      float zz = x[(size_t)(b * 3 + 2) * NN + i];
      px[r] = xx; py[r] = yy; pz[r] = zz;
      float ox = xx, oy = yy, oz = zz;
      asm volatile("" : "+v"(ox), "+v"(oy), "+v"(oz));  // kill LDS<->reg CSE
      float4 o4 = {ox, oy, oz, 0.f};
      sxyz[i] = o4;
      ds[r] = 1e10f;
    }
    __syncthreads();
    int far = 0; int p = 0;
    for (int it = 0; it < SS1; it++) {
      float4 f4 = sxyz[far];
      float fx = f4.x, fy = f4.y, fz = f4.z;
      if (t == 0) {
        fps1[b * SS1 + it] = far;
        size_t ob = ((size_t)b * SS1 + it) * 3;
        nx1[ob] = fx; nx1[ob + 1] = fy; nx1[ob + 2] = fz;
        c4[it] = f4;
      }
      float mm0 = -1.f, mm1 = -1.f, mm2 = -1.f, mm3 = -1.f;
#pragma unroll
      for (int r = 0; r < PPL; r++) {
        float dx = px[r] - fx, dy = py[r] - fy, dz = pz[r] - fz;
        float d = dx * dx + dy * dy + dz * dz;
        float nd = d < ds[r] ? d : ds[r];
        ds[r] = nd;
        if ((r & 3) == 0) mm0 = nd > mm0 ? nd : mm0;
        else if ((r & 3) == 1) mm1 = nd > mm1 ? nd : mm1;
        else if ((r & 3) == 2) mm2 = nd > mm2 ? nd : mm2;
        else mm3 = nd > mm3 ? nd : mm3;
      }
      float m = fmaxf(fmaxf(mm0, mm1), fmaxf(mm2, mm3));
      int cand[PPL];
#pragma unroll
      for (int r = 0; r < PPL; r++) cand[r] = (ds[r] == m) ? (r * 256 + t) : 0x7fffffff;
#pragma unroll
      for (int st = PPL / 2; st > 0; st >>= 1)
#pragma unroll
        for (int r = 0; r < st; r++) cand[r] = cand[r] < cand[r + st] ? cand[r] : cand[r + st];
      unsigned hi = __float_as_uint(m);
      unsigned lo = (unsigned)cand[0];
      dpp_chain_maxv_minidx(hi, lo);
      unsigned rh = (unsigned)__builtin_amdgcn_readlane((int)hi, 63);  // full exec
      unsigned rl = (unsigned)__builtin_amdgcn_readlane((int)lo, 63);
      if (lane == 0) { combH[p][w] = rh; combL[p][w] = rl; }  // 1-lane store (no same-addr pileup)
      __syncthreads();
      unsigned bh = combH[p][0], bl = combL[p][0];
#pragma unroll
      for (int ww = 1; ww < 4; ww++) {
        unsigned oh = combH[p][ww], ol = combL[p][ww];
        bool take = (oh > bh) || (oh == bh && ol < bl);
        bh = take ? oh : bh; bl = take ? ol : bl;
      }
      far = (int)bl;
      p ^= 1;
    }
    // ---- stage 2: single wave, 512 pts in regs (8/lane), NO barriers.
    __syncthreads();
    if (t >= 64) return;
    float qx[8], qy[8], qz[8], es[8];
#pragma unroll
    for (int r = 0; r < 8; r++) {
      float4 v = c4[r * 64 + t];
      qx[r] = v.x; qy[r] = v.y; qz[r] = v.z; es[r] = 1e10f;
    }
    int far2 = 0;
    for (int it = 0; it < SS2; it++) {
      float4 f4 = c4[far2];
      float fx = f4.x, fy = f4.y, fz = f4.z;
      if (t == 0) {
        fps2[b * SS2 + it] = far2;
        size_t ob = ((size_t)b * SS2 + it) * 3;
        nx2[ob] = fx; nx2[ob + 1] = fy; nx2[ob + 2] = fz;
      }
      float mm0 = -1.f, mm1 = -1.f, mm2 = -1.f, mm3 = -1.f;
#pragma unroll
      for (int r = 0; r < 8; r++) {
        float dx = qx[r] - fx, dy = qy[r] - fy, dz = qz[r] - fz;
        float d = dx * dx + dy * dy + dz * dz;
        float nd = d < es[r] ? d : es[r];
        es[r] = nd;
        if ((r & 3) == 0) mm0 = nd > mm0 ? nd : mm0;
        else if ((r & 3) == 1) mm1 = nd > mm1 ? nd : mm1;
        else if ((r & 3) == 2) mm2 = nd > mm2 ? nd : mm2;
        else mm3 = nd > mm3 ? nd : mm3;
      }
      float m = fmaxf(fmaxf(mm0, mm1), fmaxf(mm2, mm3));
      int cand[8];
#pragma unroll
      for (int r = 0; r < 8; r++) cand[r] = (es[r] == m) ? (r * 64 + t) : 0x7fffffff;
#pragma unroll
      for (int st = 4; st > 0; st >>= 1)
#pragma unroll
        for (int r = 0; r < st; r++) cand[r] = cand[r] < cand[r + st] ? cand[r] : cand[r + st];
      unsigned hi = __float_as_uint(m), lo = (unsigned)cand[0];
      dpp_chain_maxv_minidx(hi, lo);
      far2 = __builtin_amdgcn_readlane((int)lo, 63);
    }
    return;
  }
  blk -= BB;
  if (blk < 8192) {
    __shared__ float ls[64], lq[64];
    if (t < 64) { ls[t] = 0.f; lq[t] = 0.f; }
    __syncthreads();
    int o = t & 63;
    int pt = blk * 4 + (t >> 6);
    int b = pt >> 11, n = pt & (NN - 1);
    float x0 = x[(size_t)(b * 3 + 0) * NN + n];
    float x1 = x[(size_t)(b * 3 + 1) * NN + n];
    float x2 = x[(size_t)(b * 3 + 2) * NN + n];
    float v = x0 * emb_w1[o * 3] + x1 * emb_w1[o * 3 + 1] + x2 * emb_w1[o * 3 + 2];
    fA[(size_t)pt * 64 + o] = v;
    atomicAdd(&ls[o], v);
    atomicAdd(&lq[o], v * v);
    __syncthreads();
    if (t < 64) {
      int rep = blk & 63;
      atomicAdd(&rsE1[(size_t)rep * 64 + t], (double)ls[t]);
      atomicAdd(&rqE1[(size_t)rep * 64 + t], (double)lq[t]);
    }
    fin_tail(cntE1, 8192, rsE1, rqE1, 64, BB * NN, emb_g1, emb_b1, sc_e1, sh_e1);
    return;
  }
  blk -= 8192;
  if (blk < 64) { int i = blk * 256 + t; wb11[i] = __float2bfloat16(w11f[i]); return; }
  blk -= 64;
  if (blk < 64) { int i = blk * 256 + t; wb12[i] = __float2bfloat16(w12f[i]); return; }
  blk -= 64;
  if (blk < 512) { int i = blk * 256 + t; wb21[i] = __float2bfloat16(w21f[i]); return; }
  blk -= 512;
  { int i = blk * 256 + t; wb22[i] = __float2bfloat16(w22f[i]); }
}

// ================================================================ MEGA2
__global__ __launch_bounds__(256) void k_mega2(
    const float* __restrict__ x, const float* __restrict__ nx1, int* __restrict__ knn1,
    const float* __restrict__ nx2, int* __restrict__ knn2,
    const float* __restrict__ fA, const float* __restrict__ sce1,
    const float* __restrict__ she1, const float* __restrict__ w2,
    float* __restrict__ fB, double* __restrict__ rsE2, double* __restrict__ rqE2,
    unsigned* __restrict__ cntE2, const float* __restrict__ emb_g2,
    const float* __restrict__ emb_b2, float* __restrict__ sc_e2, float* __restrict__ sh_e2) {
  int blk = blockIdx.x; int t = threadIdx.x;
  if (blk < 2048) {
    constexpr int PPL = NN / 64;  // 32
    int lane = t & 63;
    int center = blk * 4 + (t >> 6);
    int b = center >> 9;
    float cx = nx1[(size_t)center * 3], cy = nx1[(size_t)center * 3 + 1],
          cz = nx1[(size_t)center * 3 + 2];
    float cn = cx * cx + cy * cy + cz * cz;
    float d2[PPL];
#pragma unroll
    for (int r = 0; r < PPL; r++) {
      int i = r * 64 + lane;
      float xx = x[(size_t)(b * 3 + 0) * NN + i];
      float yy = x[(size_t)(b * 3 + 1) * NN + i];
      float zz = x[(size_t)(b * 3 + 2) * NN + i];
      d2[r] = cn - 2.f * (cx * xx + cy * yy + cz * zz) + (xx * xx + yy * yy + zz * zz);
    }
    for (int kk = 0; kk < KNb; kk++) {
      float a0 = d2[0], a1 = d2[1], a2 = d2[2], a3 = d2[3];
#pragma unroll
      for (int r = 4; r < PPL; r += 4) {
        a0 = fminf(a0, d2[r]); a1 = fminf(a1, d2[r + 1]);
        a2 = fminf(a2, d2[r + 2]); a3 = fminf(a3, d2[r + 3]);
      }
      float m = fminf(fminf(a0, a1), fminf(a2, a3));
      int cand[PPL];
#pragma unroll
      for (int r = 0; r < PPL; r++) cand[r] = (d2[r] == m) ? (r * 64 + lane) : 0x7fffffff;
#pragma unroll
      for (int st = PPL / 2; st > 0; st >>= 1)
#pragma unroll
        for (int r = 0; r < st; r++) cand[r] = cand[r] < cand[r + st] ? cand[r] : cand[r + st];
      int widx = dpp_reduce_min_idx(fmono(m), (unsigned)cand[0]);
      if (lane == 0) knn1[(size_t)center * KNb + kk] = widx;
      int wr = widx >> 6, wl = widx & 63;
#pragma unroll
      for (int r = 0; r < PPL; r++) d2[r] = (r == wr && lane == wl) ? 3.4e38f : d2[r];
    }
    return;
  }
  blk -= 2048;
  if (blk < 1024) {
    constexpr int PPL = SS1 / 64;  // 8
    int lane = t & 63;
    int center = blk * 4 + (t >> 6);
    int b = center >> 8;
    float cx = nx2[(size_t)center * 3], cy = nx2[(size_t)center * 3 + 1],
          cz = nx2[(size_t)center * 3 + 2];
    float cn = cx * cx + cy * cy + cz * cz;
    float d2[PPL];
#pragma unroll
    for (int r = 0; r < PPL; r++) {
      int i = r * 64 + lane;
      size_t pb = ((size_t)b * SS1 + i) * 3;
      float xx = nx1[pb], yy = nx1[pb + 1], zz = nx1[pb + 2];
      d2[r] = cn - 2.f * (cx * xx + cy * yy + cz * zz) + (xx * xx + yy * yy + zz * zz);
    }
    for (int kk = 0; kk < KNb; kk++) {
      float a0 = d2[0], a1 = d2[1], a2 = d2[2], a3 = d2[3];
      a0 = fminf(a0, d2[4]); a1 = fminf(a1, d2[5]);
      a2 = fminf(a2, d2[6]); a3 = fminf(a3, d2[7]);
      float m = fminf(fminf(a0, a1), fminf(a2, a3));
      int cand[PPL];
#pragma unroll
      for (int r = 0; r < PPL; r++) cand[r] = (d2[r] == m) ? (r * 64 + lane) : 0x7fffffff;
#pragma unroll
      for (int st = PPL / 2; st > 0; st >>= 1)
#pragma unroll
        for (int r = 0; r < st; r++) cand[r] = cand[r] < cand[r + st] ? cand[r] : cand[r + st];
      int widx = dpp_reduce_min_idx(fmono(m), (unsigned)cand[0]);
      if (lane == 0) knn2[(size_t)center * KNb + kk] = widx;
      int wr = widx >> 6, wl = widx & 63;
#pragma unroll
      for (int r = 0; r < PPL; r++) d2[r] = (r == wr && lane == wl) ? 3.4e38f : d2[r];
    }
    return;
  }
  blk -= 1024;
  // emb2: 16 points per block
  __shared__ float wT[64][65];
  __shared__ float fs[16][64];
  __shared__ float ss[64], sq[64];
#pragma unroll
  for (int k = 0; k < 16; k++) {
    int idx = k * 256 + t;
    wT[idx & 63][idx >> 6] = w2[idx];
  }
  if (t < 64) { ss[t] = 0.f; sq[t] = 0.f; }
  int pt0 = blk * 16;
#pragma unroll
  for (int it = 0; it < 4; it++) {
    int idx = it * 256 + t;
    int p = idx >> 6, c = idx & 63;
    float v = fA[(size_t)(pt0 + p) * 64 + c];
    v = fmaxf(v * sce1[c] + she1[c], 0.f);
    fs[p][c] = v;
  }
  __syncthreads();
#pragma unroll
  for (int it = 0; it < 4; it++) {
    int idx = it * 256 + t;
    int p = idx >> 6, o = idx & 63;
    float acc = 0.f;
#pragma unroll 8
    for (int c = 0; c < 64; c++) acc += fs[p][c] * wT[c][o];
    fB[(size_t)(pt0 + p) * 64 + o] = acc;
    atomicAdd(&ss[o], acc);
    atomicAdd(&sq[o], acc * acc);
  }
  __syncthreads();
  if (t < 64) {
    int rep = blk & 63;
    atomicAdd(&rsE2[(size_t)rep * 64 + t], (double)ss[t]);
    atomicAdd(&rqE2[(size_t)rep * 64 + t], (double)sq[t]);
  }
  fin_tail(cntE2, 2048, rsE2, rqE2, 64, BB * NN, emb_g2, emb_b2, sc_e2, sh_e2);
}

// ---------------------------------------------------------------- gather: A = [rel | cf] bf16
template <int D, bool BN>
__global__ __launch_bounds__(256) void k_gather(const float* __restrict__ feat, int N,
                                                const int* __restrict__ fpsidx,
                                                const int* __restrict__ knn, int S,
                                                const float* __restrict__ bnsc,
                                                const float* __restrict__ bnsh,
                                                __hip_bfloat16* __restrict__ A) {
  int blk = blockIdx.x; int b = blk / S; int t = threadIdx.x;
  __shared__ float cf[D]; __shared__ int nbr[KNb];
  if (t < KNb) nbr[t] = knn[(size_t)blk * KNb + t];
  int center = fpsidx[blk];
  for (int c = t; c < D; c += 256) {
    float v = feat[((size_t)b * N + center) * D + c];
    if constexpr (BN) v = fmaxf(v * bnsc[c] + bnsh[c], 0.f);
    cf[c] = v;
  }
  __syncthreads();
  for (int i = t; i < KNb * D; i += 256) {
    int kk = i / D, c = i - kk * D;
    float v = feat[((size_t)b * N + nbr[kk]) * D + c];
    if constexpr (BN) v = fmaxf(v * bnsc[c] + bnsh[c], 0.f);
    size_t row = (size_t)blk * KNb + kk;
    A[row * (2 * D) + c] = __float2bfloat16(v - cf[c]);
    A[row * (2 * D) + D + c] = __float2bfloat16(cf[c]);
  }
}

// ---------------------------------------------------------------- gather for SG2 from maxb/minb+BN
__global__ __launch_bounds__(256) void k_gather_feat(
    const float* __restrict__ maxb, const float* __restrict__ minb,
    const float* __restrict__ sc, const float* __restrict__ sh,
    const int* __restrict__ fpsidx, const int* __restrict__ knn,
    __hip_bfloat16* __restrict__ A) {
  constexpr int D = 128;
  int blk = blockIdx.x; int b = blk / SS2; int t = threadIdx.x;
  __shared__ float cf[D]; __shared__ int nbr[KNb];
  if (t < KNb) nbr[t] = knn[(size_t)blk * KNb + t];
  int center = fpsidx[blk];
  for (int c = t; c < D; c += 256) {
    size_t row = (size_t)b * SS1 + center;
    float s = sc[c];
    float sel = s > 0.f ? maxb[row * D + c] : minb[row * D + c];
    cf[c] = fmaxf(sel * s + sh[c], 0.f);
  }
  __syncthreads();
  for (int i = t; i < KNb * D; i += 256) {
    int kk = i / D, c = i - kk * D;
    size_t row = (size_t)b * SS1 + nbr[kk];
    float s = sc[c];
    float sel = s > 0.f ? maxb[row * D + c] : minb[row * D + c];
    float v = fmaxf(sel * s + sh[c], 0.f);
    size_t orow = (size_t)blk * KNb + kk;
    A[orow * (2 * D) + c] = __float2bfloat16(v - cf[c]);
    A[orow * (2 * D) + D + c] = __float2bfloat16(cf[c]);
  }
}

// ---------------------------------------------------------------- MFMA GEMM (+finalize tail)
template <int K, int EPI, bool BNA>
__global__ __launch_bounds__(256) void k_mgemm(
    const __hip_bfloat16* __restrict__ A, const __hip_bfloat16* __restrict__ W,
    int N, int Mtiles, const float* __restrict__ bias,
    const float* __restrict__ bnsc, const float* __restrict__ bnsh,
    __hip_bfloat16* __restrict__ Hout,
    float* __restrict__ maxb, float* __restrict__ minb,
    double* __restrict__ rsum, double* __restrict__ rsq,
    unsigned* __restrict__ cnt, unsigned totBlk, int rows,
    const float* __restrict__ gamma, const float* __restrict__ beta,
    float* __restrict__ outsc, float* __restrict__ outsh) {
  constexpr int SP = 40;
  int bm = blockIdx.x % Mtiles; int bn = blockIdx.x / Mtiles;
  int t = threadIdx.x; int w = t >> 6; int lane = t & 63;
  int wm = w & 1, wn = w >> 1; int quad = lane >> 4; int l15 = lane & 15;
  __shared__ short As[128 * SP];
  __shared__ short Ws[128 * SP];
  __shared__ float scs[BNA ? K : 1], shs[BNA ? K : 1];
  if constexpr (BNA) {
    for (int i = t; i < K; i += 256) { scs[i] = bnsc[i]; shs[i] = bnsh[i]; }
  }
  f32x4 acc[4][4];
  f32x4 zero = {0.f, 0.f, 0.f, 0.f};
#pragma unroll
  for (int i = 0; i < 4; i++)
#pragma unroll
    for (int j = 0; j < 4; j++) acc[i][j] = zero;

  int srow = t >> 2, sseg = t & 3;
  const short* Ag = (const short*)A;
  const short* Wg = (const short*)W;
  size_t arow0 = (size_t)bm * 128;
  size_t wrow0 = (size_t)bn * 128;

  for (int k0 = 0; k0 < K; k0 += 32) {
    __syncthreads();
    uint4 a0 = *(const uint4*)(Ag + (arow0 + srow) * K + k0 + sseg * 8);
    uint4 a1 = *(const uint4*)(Ag + (arow0 + srow + 64) * K + k0 + sseg * 8);
    uint4 b0 = *(const uint4*)(Wg + (wrow0 + srow) * K + k0 + sseg * 8);
    uint4 b1 = *(const uint4*)(Wg + (wrow0 + srow + 64) * K + k0 + sseg * 8);
    if constexpr (BNA) {
      int cb = k0 + sseg * 8;
      float s[8], h[8];
#pragma unroll
      for (int q = 0; q < 8; q++) { s[q] = scs[cb + q]; h[q] = shs[cb + q]; }
      a0.x = bn2(a0.x, s[0], h[0], s[1], h[1]);
      a0.y = bn2(a0.y, s[2], h[2], s[3], h[3]);
      a0.z = bn2(a0.z, s[4], h[4], s[5], h[5]);
      a0.w = bn2(a0.w, s[6], h[6], s[7], h[7]);
      a1.x = bn2(a1.x, s[0], h[0], s[1], h[1]);
      a1.y = bn2(a1.y, s[2], h[2], s[3], h[3]);
      a1.z = bn2(a1.z, s[4], h[4], s[5], h[5]);
      a1.w = bn2(a1.w, s[6], h[6], s[7], h[7]);
    }
    *(uint4*)(As + srow * SP + sseg * 8) = a0;
    *(uint4*)(As + (srow + 64) * SP + sseg * 8) = a1;
    *(uint4*)(Ws + srow * SP + sseg * 8) = b0;
    *(uint4*)(Ws + (srow + 64) * SP + sseg * 8) = b1;
    __syncthreads();
    bf16x8 af[4], bfr[4];
#pragma unroll
    for (int i = 0; i < 4; i++)
      af[i] = *(const bf16x8*)(As + (wm * 64 + i * 16 + l15) * SP + quad * 8);
#pragma unroll
    for (int j = 0; j < 4; j++)
      bfr[j] = *(const bf16x8*)(Ws + (wn * 64 + j * 16 + l15) * SP + quad * 8);
#pragma unroll
    for (int i = 0; i < 4; i++)
#pragma unroll
      for (int j = 0; j < 4; j++)
        acc[i][j] = __builtin_amdgcn_mfma_f32_16x16x32_bf16(af[i], bfr[j], acc[i][j], 0, 0, 0);
  }

  if constexpr (EPI == 0) {
    int rep = blockIdx.x & 63;
#pragma unroll
    for (int j = 0; j < 4; j++) {
      int col = bn * 128 + wn * 64 + j * 16 + l15;
      float bs = bias[col];
      float su = 0.f, sq = 0.f;
#pragma unroll
      for (int i = 0; i < 4; i++)
#pragma unroll
        for (int r = 0; r < 4; r++) {
          int row = bm * 128 + wm * 64 + i * 16 + quad * 4 + r;
          float v = acc[i][j][r] + bs;
          Hout[(size_t)row * N + col] = __float2bfloat16(v);
          su += v; sq += v * v;
        }
      atomicAdd(&rsum[(size_t)rep * N + col], (double)su);
      atomicAdd(&rsq[(size_t)rep * N + col], (double)sq);
    }
  } else {
    __shared__ float buf[128][33];
    for (int s = 0; s < 4; s++) {
      __syncthreads();
      if (wn == (s >> 1)) {
        int jb = 2 * (s & 1);
#pragma unroll
        for (int jj = 0; jj < 2; jj++) {
          int j = jb + jj;
          int lcol = jj * 16 + l15;
          float bs = bias[bn * 128 + s * 32 + lcol];
#pragma unroll
          for (int i = 0; i < 4; i++)
#pragma unroll
            for (int r = 0; r < 4; r++)
              buf[wm * 64 + i * 16 + quad * 4 + r][lcol] = acc[i][j][r] + bs;
        }
      }
      __syncthreads();
      if (t < 128) {
        int g = t >> 5, c = t & 31;
        float mx = -3.4e38f, mn = 3.4e38f, su = 0.f, sq = 0.f;
#pragma unroll
        for (int r = 0; r < 32; r++) {
          float v = buf[g * 32 + r][c];
          mx = fmaxf(mx, v); mn = fminf(mn, v);
          su += v; sq += v * v;
        }
        int col = bn * 128 + s * 32 + c;
        size_t gidx = (size_t)bm * 4 + g;
        maxb[gidx * N + col] = mx;
        minb[gidx * N + col] = mn;
        int rep = blockIdx.x & 63;
        atomicAdd(&rsum[(size_t)rep * N + col], (double)su);
        atomicAdd(&rsq[(size_t)rep * N + col], (double)sq);
      }
    }
  }
  fin_tail(cnt, totBlk, rsum, rsq, N, rows, gamma, beta, outsc, outsh);
}

// ---------------------------------------------------------------- final output (transposed store)
__global__ void k_final_out(const float* __restrict__ maxb, const float* __restrict__ minb,
                            const float* __restrict__ scale, const float* __restrict__ shift,
                            float* __restrict__ out) {
  int idx = blockIdx.x * blockDim.x + threadIdx.x;
  if (idx >= BB * SS2 * 512) return;
  int o = idx % 512; int si = (idx / 512) % SS2; int b = idx / (512 * SS2);
  float sc = scale[o];
  float sel = sc > 0.f ? maxb[idx] : minb[idx];
  out[((size_t)b * 512 + o) * SS2 + si] = fmaxf(sel * sc + shift[o], 0.f);
}

// ---------------------------------------------------------------- host
extern "C" void kernel_launch(void* const* d_in, const int* in_sizes, int n_in,
                              void* d_out, int out_size, void* d_ws, size_t ws_size,
                              hipStream_t stream) {
  const float* x       = (const float*)d_in[0];
  const float* emb_w1  = (const float*)d_in[1];
  const float* emb_g1  = (const float*)d_in[2];
  const float* emb_b1  = (const float*)d_in[3];
  const float* emb_w2  = (const float*)d_in[4];
  const float* emb_g2  = (const float*)d_in[5];
  const float* emb_b2  = (const float*)d_in[6];
  const float* sg1_w1  = (const float*)d_in[7];
  const float* sg1_cb1 = (const float*)d_in[8];
  const float* sg1_g1  = (const float*)d_in[9];
  const float* sg1_b1  = (const float*)d_in[10];
  const float* sg1_w2  = (const float*)d_in[11];
  const float* sg1_cb2 = (const float*)d_in[12];
  const float* sg1_g2  = (const float*)d_in[13];
  const float* sg1_b2  = (const float*)d_in[14];
  const float* sg2_w1  = (const float*)d_in[15];
  const float* sg2_cb1 = (const float*)d_in[16];
  const float* sg2_g1  = (const float*)d_in[17];
  const float* sg2_b1  = (const float*)d_in[18];
  const float* sg2_w2  = (const float*)d_in[19];
  const float* sg2_cb2 = (const float*)d_in[20];
  const float* sg2_g2  = (const float*)d_in[21];
  const float* sg2_b2  = (const float*)d_in[22];

  char* ws = (char*)d_ws;
  size_t off = 0;
  auto alloc = [&](size_t bytes) -> size_t {
    size_t cur = off; off += (bytes + 255) & ~(size_t)255; return cur;
  };
  float* fA   = (float*)(ws + alloc((size_t)BB * NN * 64 * 4));
  float* fB   = (float*)(ws + alloc((size_t)BB * NN * 64 * 4));
  float* nx1  = (float*)(ws + alloc((size_t)BB * SS1 * 3 * 4));
  float* nx2  = (float*)(ws + alloc((size_t)BB * SS2 * 3 * 4));
  int* fps1   = (int*)(ws + alloc((size_t)BB * SS1 * 4));
  int* fps2   = (int*)(ws + alloc((size_t)BB * SS2 * 4));
  int* knn1   = (int*)(ws + alloc((size_t)BB * SS1 * KNb * 4));
  int* knn2   = (int*)(ws + alloc((size_t)BB * SS2 * KNb * 4));
  float* maxb = (float*)(ws + alloc((size_t)BB * SS2 * 512 * 4));
  float* minb = (float*)(ws + alloc((size_t)BB * SS2 * 512 * 4));
  float* scbuf = (float*)(ws + alloc((size_t)12 * 512 * 4));
  float* sc11 = scbuf + 4 * 512, *sh11 = scbuf + 5 * 512;
  float* sc12 = scbuf + 6 * 512, *sh12 = scbuf + 7 * 512;
  float* sc21 = scbuf + 8 * 512, *sh21 = scbuf + 9 * 512;
  float* sc22 = scbuf + 10 * 512, *sh22 = scbuf + 11 * 512;
  float* sc_e1 = scbuf + 0 * 512, *sh_e1 = scbuf + 1 * 512;
  float* sc_e2 = scbuf + 2 * 512, *sh_e2 = scbuf + 3 * 512;
  size_t statsz = (size_t)12 * 64 * 512 * 8 + 256;  // +256B for the 6 tail counters
  char* statz = ws + alloc(statsz);
  double* st = (double*)statz;
  double* rsA = st + 0 * 64 * 512, *rqA = st + 1 * 64 * 512;
  double* rsB = st + 2 * 64 * 512, *rqB = st + 3 * 64 * 512;
  double* rsC = st + 4 * 64 * 512, *rqC = st + 5 * 64 * 512;
  double* rsD = st + 6 * 64 * 512, *rqD = st + 7 * 64 * 512;
  double* rsE1 = st + 8 * 64 * 512, *rqE1 = st + 9 * 64 * 512;
  double* rsE2 = st + 10 * 64 * 512, *rqE2 = st + 11 * 64 * 512;
  unsigned* cnts = (unsigned*)(statz + (size_t)12 * 64 * 512 * 8);
  unsigned* cntE1 = cnts + 0; unsigned* cntE2 = cnts + 1;
  unsigned* cntA = cnts + 2; unsigned* cntB = cnts + 3;
  unsigned* cntC = cnts + 4; unsigned* cntD = cnts + 5;
  __hip_bfloat16* wb11 = (__hip_bfloat16*)(ws + alloc(128 * 128 * 2));
  __hip_bfloat16* wb12 = (__hip_bfloat16*)(ws + alloc(128 * 128 * 2));
  __hip_bfloat16* wb21 = (__hip_bfloat16*)(ws + alloc(512 * 256 * 2));
  __hip_bfloat16* wb22 = (__hip_bfloat16*)(ws + alloc(512 * 512 * 2));
  __hip_bfloat16* Abuf = (__hip_bfloat16*)(ws + alloc((size_t)262144 * 128 * 2));  // 64MB
  __hip_bfloat16* Hbuf = (__hip_bfloat16*)(ws + alloc((size_t)131072 * 512 * 2));  // 128MB

  hipMemsetAsync(statz, 0, statsz, stream);

  const int thr = 256;
  // mega1: 16 fps + 8192 emb1 + (64+64+512+1024) f2bf = 9872 blocks
  k_mega1<<<9872, 256, 0, stream>>>(x, emb_w1, fA, rsE1, rqE1, fps1, nx1, fps2, nx2,
                                    sg1_w1, wb11, sg1_w2, wb12, sg2_w1, wb21, sg2_w2, wb22,
                                    cntE1, emb_g1, emb_b1, sc_e1, sh_e1);
  // mega2: 2048 knn1 + 1024 knn2 + 2048 emb2 = 5120 blocks
  k_mega2<<<5120, 256, 0, stream>>>(x, nx1, knn1, nx2, knn2, fA, sc_e1, sh_e1, emb_w2,
                                    fB, rsE2, rqE2, cntE2, emb_g2, emb_b2, sc_e2, sh_e2);

  // ---- SG1: M=262144, K=128, N=128
  k_gather<64, true><<<BB * SS1, 256, 0, stream>>>(fB, NN, fps1, knn1, SS1,
                                                   sc_e2, sh_e2, Abuf);
  k_mgemm<128, 0, false><<<2048, 256, 0, stream>>>(Abuf, wb11, 128, 2048, sg1_cb1,
                                                   nullptr, nullptr, Hbuf,
                                                   nullptr, nullptr, rsA, rqA,
                                                   cntA, 2048, 262144, sg1_g1, sg1_b1, sc11, sh11);
  k_mgemm<128, 1, true><<<2048, 256, 0, stream>>>(Hbuf, wb12, 128, 2048, sg1_cb2,
                                                  sc11, sh11, nullptr,
                                                  maxb, minb, rsB, rqB,
                                                  cntB, 2048, 262144, sg1_g2, sg1_b2, sc12, sh12);

  // ---- SG2: gather directly from maxb/minb (+BN), M=131072, K=256->512, N=512
  k_gather_feat<<<BB * SS2, 256, 0, stream>>>(maxb, minb, sc12, sh12, fps2, knn2, Abuf);
  k_mgemm<256, 0, false><<<1024 * 4, 256, 0, stream>>>(Abuf, wb21, 512, 1024, sg2_cb1,
                                                       nullptr, nullptr, Hbuf,
                                                       nullptr, nullptr, rsC, rqC,
                                                       cntC, 4096, 131072, sg2_g1, sg2_b1, sc21, sh21);
  k_mgemm<512, 1, true><<<1024 * 4, 256, 0, stream>>>(Hbuf, wb22, 512, 1024, sg2_cb2,
                                                      sc21, sh21, nullptr,
                                                      maxb, minb, rsD, rqD,
                                                      cntD, 4096, 131072, sg2_g2, sg2_b2, sc22, sh22);
  k_final_out<<<(BB * SS2 * 512 + thr - 1) / thr, thr, 0, stream>>>(maxb, minb, sc22, sh22,
                                                                    (float*)d_out);
}

// Round 13
// 1224.624 us; speedup vs baseline: 2.2578x; 2.2578x over previous
//
#include <hip/hip_runtime.h>
#include <hip/hip_bf16.h>

#define EPS_BN 1e-5f
constexpr int BB = 16, NN = 2048, SS1 = 512, SS2 = 256, KNb = 32;

typedef short bf16x8 __attribute__((ext_vector_type(8)));
typedef float f32x4 __attribute__((ext_vector_type(4)));

__device__ inline float bflo(unsigned u) { return __uint_as_float(u << 16); }
__device__ inline float bfhi(unsigned u) { return __uint_as_float(u & 0xffff0000u); }
__device__ inline unsigned short f2bf_bits(float v) {
  __hip_bfloat16 h = __float2bfloat16(v);
  return *reinterpret_cast<unsigned short*>(&h);
}
__device__ inline unsigned fmono(float v) {
  int b = __float_as_int(v);
  return (unsigned)(b ^ ((b >> 31) | 0x80000000));
}
__device__ inline unsigned bn2(unsigned u, float s0, float h0, float s1, float h1) {
  float v0 = fmaxf(bflo(u) * s0 + h0, 0.f);
  float v1 = fmaxf(bfhi(u) * s1 + h1, 0.f);
  return (unsigned)f2bf_bits(v0) | ((unsigned)f2bf_bits(v1) << 16);
}

// ---- DPP compound-key wave64 reduction (round-6 lesson: DPP+readlane at full exec)
// ---- round-12 lesson: NO per-block __threadfence() in hot kernels (L2 flush!)
template <int CTRL>
__device__ inline void dpp_step_min(unsigned& hi, unsigned& lo) {
  unsigned hs = (unsigned)__builtin_amdgcn_update_dpp((int)hi, (int)hi, CTRL, 0xF, 0xF, false);
  unsigned ls = (unsigned)__builtin_amdgcn_update_dpp((int)lo, (int)lo, CTRL, 0xF, 0xF, false);
  bool take = (hs < hi) || (hs == hi && ls < lo);
  hi = take ? hs : hi; lo = take ? ls : lo;
}
template <int CTRL>
__device__ inline void dpp_step_maxv_minidx(unsigned& hi, unsigned& lo) {
  unsigned hs = (unsigned)__builtin_amdgcn_update_dpp((int)hi, (int)hi, CTRL, 0xF, 0xF, false);
  unsigned ls = (unsigned)__builtin_amdgcn_update_dpp((int)lo, (int)lo, CTRL, 0xF, 0xF, false);
  bool take = (hs > hi) || (hs == hi && ls < lo);
  hi = take ? hs : hi; lo = take ? ls : lo;
}
__device__ inline void dpp_chain_min(unsigned& hi, unsigned& lo) {
  dpp_step_min<0x111>(hi, lo); dpp_step_min<0x112>(hi, lo);
  dpp_step_min<0x114>(hi, lo); dpp_step_min<0x118>(hi, lo);
  dpp_step_min<0x142>(hi, lo); dpp_step_min<0x143>(hi, lo);
}
__device__ inline void dpp_chain_maxv_minidx(unsigned& hi, unsigned& lo) {
  dpp_step_maxv_minidx<0x111>(hi, lo); dpp_step_maxv_minidx<0x112>(hi, lo);
  dpp_step_maxv_minidx<0x114>(hi, lo); dpp_step_maxv_minidx<0x118>(hi, lo);
  dpp_step_maxv_minidx<0x142>(hi, lo); dpp_step_maxv_minidx<0x143>(hi, lo);
}
__device__ inline int dpp_reduce_min_idx(unsigned hi, unsigned lo) {
  dpp_chain_min(hi, lo);
  return __builtin_amdgcn_readlane((int)lo, 63);
}

// ================================================================ MEGA1
__global__ __launch_bounds__(256, 1) void k_mega1(
    const float* __restrict__ x, const float* __restrict__ emb_w1,
    float* __restrict__ fA, double* __restrict__ rsE1, double* __restrict__ rqE1,
    int* __restrict__ fps1, float* __restrict__ nx1,
    int* __restrict__ fps2, float* __restrict__ nx2,
    const float* __restrict__ w11f, __hip_bfloat16* __restrict__ wb11,
    const float* __restrict__ w12f, __hip_bfloat16* __restrict__ wb12,
    const float* __restrict__ w21f, __hip_bfloat16* __restrict__ wb21,
    const float* __restrict__ w22f, __hip_bfloat16* __restrict__ wb22) {
  int blk = blockIdx.x;
  int t = threadIdx.x;
  if (blk < BB) {
    constexpr int PPL = NN / 256;   // 8
    int b = blk; int w = t >> 6; int lane = t & 63;
    __shared__ float4 sxyz[NN];
    __shared__ float4 c4[SS1];
    __shared__ unsigned combH[2][4], combL[2][4];
    float px[PPL], py[PPL], pz[PPL], ds[PPL];
#pragma unroll
    for (int r = 0; r < PPL; r++) {
      int i = r * 256 + t;
      float xx = x[(size_t)(b * 3 + 0) * NN + i];
      float yy = x[(size_t)(b * 3 + 1) * NN + i];
      float zz = x[(size_t)(b * 3 + 2) * NN + i];
      px[r] = xx; py[r] = yy; pz[r] = zz;
      float ox = xx, oy = yy, oz = zz;
      asm volatile("" : "+v"(ox), "+v"(oy), "+v"(oz));  // kill LDS<->reg CSE
      float4 o4 = {ox, oy, oz, 0.f};
      sxyz[i] = o4;
      ds[r] = 1e10f;
    }
    __syncthreads();
    int far = 0; int p = 0;
    for (int it = 0; it < SS1; it++) {
      float4 f4 = sxyz[far];
      float fx = f4.x, fy = f4.y, fz = f4.z;
      if (t == 0) {
        fps1[b * SS1 + it] = far;
        size_t ob = ((size_t)b * SS1 + it) * 3;
        nx1[ob] = fx; nx1[ob + 1] = fy; nx1[ob + 2] = fz;
        c4[it] = f4;
      }
      float mm0 = -1.f, mm1 = -1.f, mm2 = -1.f, mm3 = -1.f;
#pragma unroll
      for (int r = 0; r < PPL; r++) {
        float dx = px[r] - fx, dy = py[r] - fy, dz = pz[r] - fz;
        float d = dx * dx + dy * dy + dz * dz;
        float nd = d < ds[r] ? d : ds[r];
        ds[r] = nd;
        if ((r & 3) == 0) mm0 = nd > mm0 ? nd : mm0;
        else if ((r & 3) == 1) mm1 = nd > mm1 ? nd : mm1;
        else if ((r & 3) == 2) mm2 = nd > mm2 ? nd : mm2;
        else mm3 = nd > mm3 ? nd : mm3;
      }
      float m = fmaxf(fmaxf(mm0, mm1), fmaxf(mm2, mm3));
      int cand[PPL];
#pragma unroll
      for (int r = 0; r < PPL; r++) cand[r] = (ds[r] == m) ? (r * 256 + t) : 0x7fffffff;
#pragma unroll
      for (int st = PPL / 2; st > 0; st >>= 1)
#pragma unroll
        for (int r = 0; r < st; r++) cand[r] = cand[r] < cand[r + st] ? cand[r] : cand[r + st];
      unsigned hi = __float_as_uint(m);
      unsigned lo = (unsigned)cand[0];
      dpp_chain_maxv_minidx(hi, lo);
      unsigned rh = (unsigned)__builtin_amdgcn_readlane((int)hi, 63);  // full exec
      unsigned rl = (unsigned)__builtin_amdgcn_readlane((int)lo, 63);
      if (lane == 0) { combH[p][w] = rh; combL[p][w] = rl; }  // 1-lane store
      __syncthreads();
      unsigned bh = combH[p][0], bl = combL[p][0];
#pragma unroll
      for (int ww = 1; ww < 4; ww++) {
        unsigned oh = combH[p][ww], ol = combL[p][ww];
        bool take = (oh > bh) || (oh == bh && ol < bl);
        bh = take ? oh : bh; bl = take ? ol : bl;
      }
      far = (int)bl;
      p ^= 1;
    }
    // ---- stage 2: single wave, 512 pts in regs (8/lane), NO barriers.
    __syncthreads();
    if (t >= 64) return;
    float qx[8], qy[8], qz[8], es[8];
#pragma unroll
    for (int r = 0; r < 8; r++) {
      float4 v = c4[r * 64 + t];
      qx[r] = v.x; qy[r] = v.y; qz[r] = v.z; es[r] = 1e10f;
    }
    int far2 = 0;
    for (int it = 0; it < SS2; it++) {
      float4 f4 = c4[far2];
      float fx = f4.x, fy = f4.y, fz = f4.z;
      if (t == 0) {
        fps2[b * SS2 + it] = far2;
        size_t ob = ((size_t)b * SS2 + it) * 3;
        nx2[ob] = fx; nx2[ob + 1] = fy; nx2[ob + 2] = fz;
      }
      float mm0 = -1.f, mm1 = -1.f, mm2 = -1.f, mm3 = -1.f;
#pragma unroll
      for (int r = 0; r < 8; r++) {
        float dx = qx[r] - fx, dy = qy[r] - fy, dz = qz[r] - fz;
        float d = dx * dx + dy * dy + dz * dz;
        float nd = d < es[r] ? d : es[r];
        es[r] = nd;
        if ((r & 3) == 0) mm0 = nd > mm0 ? nd : mm0;
        else if ((r & 3) == 1) mm1 = nd > mm1 ? nd : mm1;
        else if ((r & 3) == 2) mm2 = nd > mm2 ? nd : mm2;
        else mm3 = nd > mm3 ? nd : mm3;
      }
      float m = fmaxf(fmaxf(mm0, mm1), fmaxf(mm2, mm3));
      int cand[8];
#pragma unroll
      for (int r = 0; r < 8; r++) cand[r] = (es[r] == m) ? (r * 64 + t) : 0x7fffffff;
#pragma unroll
      for (int st = 4; st > 0; st >>= 1)
#pragma unroll
        for (int r = 0; r < st; r++) cand[r] = cand[r] < cand[r + st] ? cand[r] : cand[r + st];
      unsigned hi = __float_as_uint(m), lo = (unsigned)cand[0];
      dpp_chain_maxv_minidx(hi, lo);
      far2 = __builtin_amdgcn_readlane((int)lo, 63);
    }
    return;
  }
  blk -= BB;
  if (blk < 8192) {
    __shared__ float ls[64], lq[64];
    if (t < 64) { ls[t] = 0.f; lq[t] = 0.f; }
    __syncthreads();
    int o = t & 63;
    int pt = blk * 4 + (t >> 6);
    int b = pt >> 11, n = pt & (NN - 1);
    float x0 = x[(size_t)(b * 3 + 0) * NN + n];
    float x1 = x[(size_t)(b * 3 + 1) * NN + n];
    float x2 = x[(size_t)(b * 3 + 2) * NN + n];
    float v = x0 * emb_w1[o * 3] + x1 * emb_w1[o * 3 + 1] + x2 * emb_w1[o * 3 + 2];
    fA[(size_t)pt * 64 + o] = v;
    atomicAdd(&ls[o], v);
    atomicAdd(&lq[o], v * v);
    __syncthreads();
    if (t < 64) {
      int rep = blk & 63;
      atomicAdd(&rsE1[(size_t)rep * 64 + t], (double)ls[t]);
      atomicAdd(&rqE1[(size_t)rep * 64 + t], (double)lq[t]);
    }
    return;
  }
  blk -= 8192;
  if (blk < 64) { int i = blk * 256 + t; wb11[i] = __float2bfloat16(w11f[i]); return; }
  blk -= 64;
  if (blk < 64) { int i = blk * 256 + t; wb12[i] = __float2bfloat16(w12f[i]); return; }
  blk -= 64;
  if (blk < 512) { int i = blk * 256 + t; wb21[i] = __float2bfloat16(w21f[i]); return; }
  blk -= 512;
  { int i = blk * 256 + t; wb22[i] = __float2bfloat16(w22f[i]); }
}

// ================================================================ MEGA2
__global__ __launch_bounds__(256) void k_mega2(
    const float* __restrict__ x, const float* __restrict__ nx1, int* __restrict__ knn1,
    const float* __restrict__ nx2, int* __restrict__ knn2,
    const float* __restrict__ fA, const float* __restrict__ sce1,
    const float* __restrict__ she1, const float* __restrict__ w2,
    float* __restrict__ fB, double* __restrict__ rsE2, double* __restrict__ rqE2) {
  int blk = blockIdx.x; int t = threadIdx.x;
  if (blk < 2048) {
    constexpr int PPL = NN / 64;  // 32
    int lane = t & 63;
    int center = blk * 4 + (t >> 6);
    int b = center >> 9;
    float cx = nx1[(size_t)center * 3], cy = nx1[(size_t)center * 3 + 1],
          cz = nx1[(size_t)center * 3 + 2];
    float cn = cx * cx + cy * cy + cz * cz;
    float d2[PPL];
#pragma unroll
    for (int r = 0; r < PPL; r++) {
      int i = r * 64 + lane;
      float xx = x[(size_t)(b * 3 + 0) * NN + i];
      float yy = x[(size_t)(b * 3 + 1) * NN + i];
      float zz = x[(size_t)(b * 3 + 2) * NN + i];
      d2[r] = cn - 2.f * (cx * xx + cy * yy + cz * zz) + (xx * xx + yy * yy + zz * zz);
    }
    for (int kk = 0; kk < KNb; kk++) {
      float a0 = d2[0], a1 = d2[1], a2 = d2[2], a3 = d2[3];
#pragma unroll
      for (int r = 4; r < PPL; r += 4) {
        a0 = fminf(a0, d2[r]); a1 = fminf(a1, d2[r + 1]);
        a2 = fminf(a2, d2[r + 2]); a3 = fminf(a3, d2[r + 3]);
      }
      float m = fminf(fminf(a0, a1), fminf(a2, a3));
      int cand[PPL];
#pragma unroll
      for (int r = 0; r < PPL; r++) cand[r] = (d2[r] == m) ? (r * 64 + lane) : 0x7fffffff;
#pragma unroll
      for (int st = PPL / 2; st > 0; st >>= 1)
#pragma unroll
        for (int r = 0; r < st; r++) cand[r] = cand[r] < cand[r + st] ? cand[r] : cand[r + st];
      int widx = dpp_reduce_min_idx(fmono(m), (unsigned)cand[0]);
      if (lane == 0) knn1[(size_t)center * KNb + kk] = widx;
      int wr = widx >> 6, wl = widx & 63;
#pragma unroll
      for (int r = 0; r < PPL; r++) d2[r] = (r == wr && lane == wl) ? 3.4e38f : d2[r];
    }
    return;
  }
  blk -= 2048;
  if (blk < 1024) {
    constexpr int PPL = SS1 / 64;  // 8
    int lane = t & 63;
    int center = blk * 4 + (t >> 6);
    int b = center >> 8;
    float cx = nx2[(size_t)center * 3], cy = nx2[(size_t)center * 3 + 1],
          cz = nx2[(size_t)center * 3 + 2];
    float cn = cx * cx + cy * cy + cz * cz;
    float d2[PPL];
#pragma unroll
    for (int r = 0; r < PPL; r++) {
      int i = r * 64 + lane;
      size_t pb = ((size_t)b * SS1 + i) * 3;
      float xx = nx1[pb], yy = nx1[pb + 1], zz = nx1[pb + 2];
      d2[r] = cn - 2.f * (cx * xx + cy * yy + cz * zz) + (xx * xx + yy * yy + zz * zz);
    }
    for (int kk = 0; kk < KNb; kk++) {
      float a0 = d2[0], a1 = d2[1], a2 = d2[2], a3 = d2[3];
      a0 = fminf(a0, d2[4]); a1 = fminf(a1, d2[5]);
      a2 = fminf(a2, d2[6]); a3 = fminf(a3, d2[7]);
      float m = fminf(fminf(a0, a1), fminf(a2, a3));
      int cand[PPL];
#pragma unroll
      for (int r = 0; r < PPL; r++) cand[r] = (d2[r] == m) ? (r * 64 + lane) : 0x7fffffff;
#pragma unroll
      for (int st = PPL / 2; st > 0; st >>= 1)
#pragma unroll
        for (int r = 0; r < st; r++) cand[r] = cand[r] < cand[r + st] ? cand[r] : cand[r + st];
      int widx = dpp_reduce_min_idx(fmono(m), (unsigned)cand[0]);
      if (lane == 0) knn2[(size_t)center * KNb + kk] = widx;
      int wr = widx >> 6, wl = widx & 63;
#pragma unroll
      for (int r = 0; r < PPL; r++) d2[r] = (r == wr && lane == wl) ? 3.4e38f : d2[r];
    }
    return;
  }
  blk -= 1024;
  // emb2: 16 points per block
  __shared__ float wT[64][65];
  __shared__ float fs[16][64];
  __shared__ float ss[64], sq[64];
#pragma unroll
  for (int k = 0; k < 16; k++) {
    int idx = k * 256 + t;
    wT[idx & 63][idx >> 6] = w2[idx];
  }
  if (t < 64) { ss[t] = 0.f; sq[t] = 0.f; }
  int pt0 = blk * 16;
#pragma unroll
  for (int it = 0; it < 4; it++) {
    int idx = it * 256 + t;
    int p = idx >> 6, c = idx & 63;
    float v = fA[(size_t)(pt0 + p) * 64 + c];
    v = fmaxf(v * sce1[c] + she1[c], 0.f);
    fs[p][c] = v;
  }
  __syncthreads();
#pragma unroll
  for (int it = 0; it < 4; it++) {
    int idx = it * 256 + t;
    int p = idx >> 6, o = idx & 63;
    float acc = 0.f;
#pragma unroll 8
    for (int c = 0; c < 64; c++) acc += fs[p][c] * wT[c][o];
    fB[(size_t)(pt0 + p) * 64 + o] = acc;
    atomicAdd(&ss[o], acc);
    atomicAdd(&sq[o], acc * acc);
  }
  __syncthreads();
  if (t < 64) {
    int rep = blk & 63;
    atomicAdd(&rsE2[(size_t)rep * 64 + t], (double)ss[t]);
    atomicAdd(&rqE2[(size_t)rep * 64 + t], (double)sq[t]);
  }
}

// ---------------------------------------------------------------- gather: A = [rel | cf] bf16
template <int D, bool BN>
__global__ __launch_bounds__(256) void k_gather(const float* __restrict__ feat, int N,
                                                const int* __restrict__ fpsidx,
                                                const int* __restrict__ knn, int S,
                                                const float* __restrict__ bnsc,
                                                const float* __restrict__ bnsh,
                                                __hip_bfloat16* __restrict__ A) {
  int blk = blockIdx.x; int b = blk / S; int t = threadIdx.x;
  __shared__ float cf[D]; __shared__ int nbr[KNb];
  if (t < KNb) nbr[t] = knn[(size_t)blk * KNb + t];
  int center = fpsidx[blk];
  for (int c = t; c < D; c += 256) {
    float v = feat[((size_t)b * N + center) * D + c];
    if constexpr (BN) v = fmaxf(v * bnsc[c] + bnsh[c], 0.f);
    cf[c] = v;
  }
  __syncthreads();
  for (int i = t; i < KNb * D; i += 256) {
    int kk = i / D, c = i - kk * D;
    float v = feat[((size_t)b * N + nbr[kk]) * D + c];
    if constexpr (BN) v = fmaxf(v * bnsc[c] + bnsh[c], 0.f);
    size_t row = (size_t)blk * KNb + kk;
    A[row * (2 * D) + c] = __float2bfloat16(v - cf[c]);
    A[row * (2 * D) + D + c] = __float2bfloat16(cf[c]);
  }
}

// ---------------------------------------------------------------- gather for SG2 from maxb/minb+BN
__global__ __launch_bounds__(256) void k_gather_feat(
    const float* __restrict__ maxb, const float* __restrict__ minb,
    const float* __restrict__ sc, const float* __restrict__ sh,
    const int* __restrict__ fpsidx, const int* __restrict__ knn,
    __hip_bfloat16* __restrict__ A) {
  constexpr int D = 128;
  int blk = blockIdx.x; int b = blk / SS2; int t = threadIdx.x;
  __shared__ float cf[D]; __shared__ int nbr[KNb];
  if (t < KNb) nbr[t] = knn[(size_t)blk * KNb + t];
  int center = fpsidx[blk];
  for (int c = t; c < D; c += 256) {
    size_t row = (size_t)b * SS1 + center;
    float s = sc[c];
    float sel = s > 0.f ? maxb[row * D + c] : minb[row * D + c];
    cf[c] = fmaxf(sel * s + sh[c], 0.f);
  }
  __syncthreads();
  for (int i = t; i < KNb * D; i += 256) {
    int kk = i / D, c = i - kk * D;
    size_t row = (size_t)b * SS1 + nbr[kk];
    float s = sc[c];
    float sel = s > 0.f ? maxb[row * D + c] : minb[row * D + c];
    float v = fmaxf(sel * s + sh[c], 0.f);
    size_t orow = (size_t)blk * KNb + kk;
    A[orow * (2 * D) + c] = __float2bfloat16(v - cf[c]);
    A[orow * (2 * D) + D + c] = __float2bfloat16(cf[c]);
  }
}

// ---------------------------------------------------------------- MFMA GEMM
template <int K, int EPI, bool BNA>
__global__ __launch_bounds__(256) void k_mgemm(
    const __hip_bfloat16* __restrict__ A, const __hip_bfloat16* __restrict__ W,
    int N, int Mtiles, const float* __restrict__ bias,
    const float* __restrict__ bnsc, const float* __restrict__ bnsh,
    __hip_bfloat16* __restrict__ Hout,
    float* __restrict__ maxb, float* __restrict__ minb,
    double* __restrict__ rsum, double* __restrict__ rsq) {
  constexpr int SP = 40;
  int bm = blockIdx.x % Mtiles; int bn = blockIdx.x / Mtiles;
  int t = threadIdx.x; int w = t >> 6; int lane = t & 63;
  int wm = w & 1, wn = w >> 1; int quad = lane >> 4; int l15 = lane & 15;
  __shared__ short As[128 * SP];
  __shared__ short Ws[128 * SP];
  __shared__ float scs[BNA ? K : 1], shs[BNA ? K : 1];
  if constexpr (BNA) {
    for (int i = t; i < K; i += 256) { scs[i] = bnsc[i]; shs[i] = bnsh[i]; }
  }
  f32x4 acc[4][4];
  f32x4 zero = {0.f, 0.f, 0.f, 0.f};
#pragma unroll
  for (int i = 0; i < 4; i++)
#pragma unroll
    for (int j = 0; j < 4; j++) acc[i][j] = zero;

  int srow = t >> 2, sseg = t & 3;
  const short* Ag = (const short*)A;
  const short* Wg = (const short*)W;
  size_t arow0 = (size_t)bm * 128;
  size_t wrow0 = (size_t)bn * 128;

  for (int k0 = 0; k0 < K; k0 += 32) {
    __syncthreads();
    uint4 a0 = *(const uint4*)(Ag + (arow0 + srow) * K + k0 + sseg * 8);
    uint4 a1 = *(const uint4*)(Ag + (arow0 + srow + 64) * K + k0 + sseg * 8);
    uint4 b0 = *(const uint4*)(Wg + (wrow0 + srow) * K + k0 + sseg * 8);
    uint4 b1 = *(const uint4*)(Wg + (wrow0 + srow + 64) * K + k0 + sseg * 8);
    if constexpr (BNA) {
      int cb = k0 + sseg * 8;
      float s[8], h[8];
#pragma unroll
      for (int q = 0; q < 8; q++) { s[q] = scs[cb + q]; h[q] = shs[cb + q]; }
      a0.x = bn2(a0.x, s[0], h[0], s[1], h[1]);
      a0.y = bn2(a0.y, s[2], h[2], s[3], h[3]);
      a0.z = bn2(a0.z, s[4], h[4], s[5], h[5]);
      a0.w = bn2(a0.w, s[6], h[6], s[7], h[7]);
      a1.x = bn2(a1.x, s[0], h[0], s[1], h[1]);
      a1.y = bn2(a1.y, s[2], h[2], s[3], h[3]);
      a1.z = bn2(a1.z, s[4], h[4], s[5], h[5]);
      a1.w = bn2(a1.w, s[6], h[6], s[7], h[7]);
    }
    *(uint4*)(As + srow * SP + sseg * 8) = a0;
    *(uint4*)(As + (srow + 64) * SP + sseg * 8) = a1;
    *(uint4*)(Ws + srow * SP + sseg * 8) = b0;
    *(uint4*)(Ws + (srow + 64) * SP + sseg * 8) = b1;
    __syncthreads();
    bf16x8 af[4], bfr[4];
#pragma unroll
    for (int i = 0; i < 4; i++)
      af[i] = *(const bf16x8*)(As + (wm * 64 + i * 16 + l15) * SP + quad * 8);
#pragma unroll
    for (int j = 0; j < 4; j++)
      bfr[j] = *(const bf16x8*)(Ws + (wn * 64 + j * 16 + l15) * SP + quad * 8);
#pragma unroll
    for (int i = 0; i < 4; i++)
#pragma unroll
      for (int j = 0; j < 4; j++)
        acc[i][j] = __builtin_amdgcn_mfma_f32_16x16x32_bf16(af[i], bfr[j], acc[i][j], 0, 0, 0);
  }

  if constexpr (EPI == 0) {
    int rep = blockIdx.x & 63;
#pragma unroll
    for (int j = 0; j < 4; j++) {
      int col = bn * 128 + wn * 64 + j * 16 + l15;
      float bs = bias[col];
      float su = 0.f, sq = 0.f;
#pragma unroll
      for (int i = 0; i < 4; i++)
#pragma unroll
        for (int r = 0; r < 4; r++) {
          int row = bm * 128 + wm * 64 + i * 16 + quad * 4 + r;
          float v = acc[i][j][r] + bs;
          Hout[(size_t)row * N + col] = __float2bfloat16(v);
          su += v; sq += v * v;
        }
      atomicAdd(&rsum[(size_t)rep * N + col], (double)su);
      atomicAdd(&rsq[(size_t)rep * N + col], (double)sq);
    }
  } else {
    __shared__ float buf[128][33];
    for (int s = 0; s < 4; s++) {
      __syncthreads();
      if (wn == (s >> 1)) {
        int jb = 2 * (s & 1);
#pragma unroll
        for (int jj = 0; jj < 2; jj++) {
          int j = jb + jj;
          int lcol = jj * 16 + l15;
          float bs = bias[bn * 128 + s * 32 + lcol];
#pragma unroll
          for (int i = 0; i < 4; i++)
#pragma unroll
            for (int r = 0; r < 4; r++)
              buf[wm * 64 + i * 16 + quad * 4 + r][lcol] = acc[i][j][r] + bs;
        }
      }
      __syncthreads();
      if (t < 128) {
        int g = t >> 5, c = t & 31;
        float mx = -3.4e38f, mn = 3.4e38f, su = 0.f, sq = 0.f;
#pragma unroll
        for (int r = 0; r < 32; r++) {
          float v = buf[g * 32 + r][c];
          mx = fmaxf(mx, v); mn = fminf(mn, v);
          su += v; sq += v * v;
        }
        int col = bn * 128 + s * 32 + c;
        size_t gidx = (size_t)bm * 4 + g;
        maxb[gidx * N + col] = mx;
        minb[gidx * N + col] = mn;
        int rep = blockIdx.x & 63;
        atomicAdd(&rsum[(size_t)rep * N + col], (double)su);
        atomicAdd(&rsq[(size_t)rep * N + col], (double)sq);
      }
    }
  }
}

// ---------------------------------------------------------------- finalize BN stats
__global__ void k_finalize(const double* __restrict__ rsum, const double* __restrict__ rsq,
                           int O, int rows,
                           const float* __restrict__ gamma, const float* __restrict__ beta,
                           float* __restrict__ scale, float* __restrict__ shift) {
  int o = blockIdx.x * blockDim.x + threadIdx.x;
  if (o >= O) return;
  double s = 0, s2 = 0;
  for (int r = 0; r < 64; r++) { s += rsum[(size_t)r * O + o]; s2 += rsq[(size_t)r * O + o]; }
  double mean = s / rows;
  double var = s2 / rows - mean * mean;
  float sc = gamma[o] * rsqrtf((float)var + EPS_BN);
  scale[o] = sc; shift[o] = beta[o] - (float)mean * sc;
}

// ---------------------------------------------------------------- final output (transposed store)
__global__ void k_final_out(const float* __restrict__ maxb, const float* __restrict__ minb,
                            const float* __restrict__ scale, const float* __restrict__ shift,
                            float* __restrict__ out) {
  int idx = blockIdx.x * blockDim.x + threadIdx.x;
  if (idx >= BB * SS2 * 512) return;
  int o = idx % 512; int si = (idx / 512) % SS2; int b = idx / (512 * SS2);
  float sc = scale[o];
  float sel = sc > 0.f ? maxb[idx] : minb[idx];
  out[((size_t)b * 512 + o) * SS2 + si] = fmaxf(sel * sc + shift[o], 0.f);
}

// ---------------------------------------------------------------- host
extern "C" void kernel_launch(void* const* d_in, const int* in_sizes, int n_in,
                              void* d_out, int out_size, void* d_ws, size_t ws_size,
                              hipStream_t stream) {
  const float* x       = (const float*)d_in[0];
  const float* emb_w1  = (const float*)d_in[1];
  const float* emb_g1  = (const float*)d_in[2];
  const float* emb_b1  = (const float*)d_in[3];
  const float* emb_w2  = (const float*)d_in[4];
  const float* emb_g2  = (const float*)d_in[5];
  const float* emb_b2  = (const float*)d_in[6];
  const float* sg1_w1  = (const float*)d_in[7];
  const float* sg1_cb1 = (const float*)d_in[8];
  const float* sg1_g1  = (const float*)d_in[9];
  const float* sg1_b1  = (const float*)d_in[10];
  const float* sg1_w2  = (const float*)d_in[11];
  const float* sg1_cb2 = (const float*)d_in[12];
  const float* sg1_g2  = (const float*)d_in[13];
  const float* sg1_b2  = (const float*)d_in[14];
  const float* sg2_w1  = (const float*)d_in[15];
  const float* sg2_cb1 = (const float*)d_in[16];
  const float* sg2_g1  = (const float*)d_in[17];
  const float* sg2_b1  = (const float*)d_in[18];
  const float* sg2_w2  = (const float*)d_in[19];
  const float* sg2_cb2 = (const float*)d_in[20];
  const float* sg2_g2  = (const float*)d_in[21];
  const float* sg2_b2  = (const float*)d_in[22];

  char* ws = (char*)d_ws;
  size_t off = 0;
  auto alloc = [&](size_t bytes) -> size_t {
    size_t cur = off; off += (bytes + 255) & ~(size_t)255; return cur;
  };
  float* fA   = (float*)(ws + alloc((size_t)BB * NN * 64 * 4));
  float* fB   = (float*)(ws + alloc((size_t)BB * NN * 64 * 4));
  float* nx1  = (float*)(ws + alloc((size_t)BB * SS1 * 3 * 4));
  float* nx2  = (float*)(ws + alloc((size_t)BB * SS2 * 3 * 4));
  int* fps1   = (int*)(ws + alloc((size_t)BB * SS1 * 4));
  int* fps2   = (int*)(ws + alloc((size_t)BB * SS2 * 4));
  int* knn1   = (int*)(ws + alloc((size_t)BB * SS1 * KNb * 4));
  int* knn2   = (int*)(ws + alloc((size_t)BB * SS2 * KNb * 4));
  float* maxb = (float*)(ws + alloc((size_t)BB * SS2 * 512 * 4));
  float* minb = (float*)(ws + alloc((size_t)BB * SS2 * 512 * 4));
  float* scbuf = (float*)(ws + alloc((size_t)12 * 512 * 4));
  float* sc11 = scbuf + 4 * 512, *sh11 = scbuf + 5 * 512;
  float* sc12 = scbuf + 6 * 512, *sh12 = scbuf + 7 * 512;
  float* sc21 = scbuf + 8 * 512, *sh21 = scbuf + 9 * 512;
  float* sc22 = scbuf + 10 * 512, *sh22 = scbuf + 11 * 512;
  float* sc_e1 = scbuf + 0 * 512, *sh_e1 = scbuf + 1 * 512;
  float* sc_e2 = scbuf + 2 * 512, *sh_e2 = scbuf + 3 * 512;
  size_t statsz = (size_t)12 * 64 * 512 * 8;
  char* statz = ws + alloc(statsz);
  double* st = (double*)statz;
  double* rsA = st + 0 * 64 * 512, *rqA = st + 1 * 64 * 512;
  double* rsB = st + 2 * 64 * 512, *rqB = st + 3 * 64 * 512;
  double* rsC = st + 4 * 64 * 512, *rqC = st + 5 * 64 * 512;
  double* rsD = st + 6 * 64 * 512, *rqD = st + 7 * 64 * 512;
  double* rsE1 = st + 8 * 64 * 512, *rqE1 = st + 9 * 64 * 512;
  double* rsE2 = st + 10 * 64 * 512, *rqE2 = st + 11 * 64 * 512;
  __hip_bfloat16* wb11 = (__hip_bfloat16*)(ws + alloc(128 * 128 * 2));
  __hip_bfloat16* wb12 = (__hip_bfloat16*)(ws + alloc(128 * 128 * 2));
  __hip_bfloat16* wb21 = (__hip_bfloat16*)(ws + alloc(512 * 256 * 2));
  __hip_bfloat16* wb22 = (__hip_bfloat16*)(ws + alloc(512 * 512 * 2));
  __hip_bfloat16* Abuf = (__hip_bfloat16*)(ws + alloc((size_t)262144 * 128 * 2));  // 64MB
  __hip_bfloat16* Hbuf = (__hip_bfloat16*)(ws + alloc((size_t)131072 * 512 * 2));  // 128MB

  hipMemsetAsync(statz, 0, statsz, stream);

  const int thr = 256;
  // mega1: 16 fps + 8192 emb1 + (64+64+512+1024) f2bf = 9872 blocks
  k_mega1<<<9872, 256, 0, stream>>>(x, emb_w1, fA, rsE1, rqE1, fps1, nx1, fps2, nx2,
                                    sg1_w1, wb11, sg1_w2, wb12, sg2_w1, wb21, sg2_w2, wb22);
  k_finalize<<<1, 64, 0, stream>>>(rsE1, rqE1, 64, BB * NN, emb_g1, emb_b1, sc_e1, sh_e1);
  // mega2: 2048 knn1 + 1024 knn2 + 2048 emb2 = 5120 blocks
  k_mega2<<<5120, 256, 0, stream>>>(x, nx1, knn1, nx2, knn2, fA, sc_e1, sh_e1, emb_w2,
                                    fB, rsE2, rqE2);
  k_finalize<<<1, 64, 0, stream>>>(rsE2, rqE2, 64, BB * NN, emb_g2, emb_b2, sc_e2, sh_e2);

  // ---- SG1: M=262144, K=128, N=128
  k_gather<64, true><<<BB * SS1, 256, 0, stream>>>(fB, NN, fps1, knn1, SS1,
                                                   sc_e2, sh_e2, Abuf);
  k_mgemm<128, 0, false><<<2048, 256, 0, stream>>>(Abuf, wb11, 128, 2048, sg1_cb1,
                                                   nullptr, nullptr, Hbuf,
                                                   nullptr, nullptr, rsA, rqA);
  k_finalize<<<1, 128, 0, stream>>>(rsA, rqA, 128, 262144, sg1_g1, sg1_b1, sc11, sh11);
  k_mgemm<128, 1, true><<<2048, 256, 0, stream>>>(Hbuf, wb12, 128, 2048, sg1_cb2,
                                                  sc11, sh11, nullptr,
                                                  maxb, minb, rsB, rqB);
  k_finalize<<<1, 128, 0, stream>>>(rsB, rqB, 128, 262144, sg1_g2, sg1_b2, sc12, sh12);

  // ---- SG2: gather directly from maxb/minb (+BN), M=131072, K=256->512, N=512
  k_gather_feat<<<BB * SS2, 256, 0, stream>>>(maxb, minb, sc12, sh12, fps2, knn2, Abuf);
  k_mgemm<256, 0, false><<<1024 * 4, 256, 0, stream>>>(Abuf, wb21, 512, 1024, sg2_cb1,
                                                       nullptr, nullptr, Hbuf,
                                                       nullptr, nullptr, rsC, rqC);
  k_finalize<<<4, 128, 0, stream>>>(rsC, rqC, 512, 131072, sg2_g1, sg2_b1, sc21, sh21);
  k_mgemm<512, 1, true><<<1024 * 4, 256, 0, stream>>>(Hbuf, wb22, 512, 1024, sg2_cb2,
                                                      sc21, sh21, nullptr,
                                                      maxb, minb, rsD, rqD);
  k_finalize<<<4, 128, 0, stream>>>(rsD, rqD, 512, 131072, sg2_g2, sg2_b2, sc22, sh22);
  k_final_out<<<(BB * SS2 * 512 + thr - 1) / thr, thr, 0, stream>>>(maxb, minb, sc22, sh22,
                                                                    (float*)d_out);
}

// Round 14
// 1205.842 us; speedup vs baseline: 2.2929x; 1.0156x over previous
//
#include <hip/hip_runtime.h>
#include <hip/hip_bf16.h>

#define EPS_BN 1e-5f
constexpr int BB = 16, NN = 2048, SS1 = 512, SS2 = 256, KNb = 32;

typedef short bf16x8 __attribute__((ext_vector_type(8)));
typedef float f32x4 __attribute__((ext_vector_type(4)));

__device__ inline float bflo(unsigned u) { return __uint_as_float(u << 16); }
__device__ inline float bfhi(unsigned u) { return __uint_as_float(u & 0xffff0000u); }
__device__ inline unsigned short f2bf_bits(float v) {
  __hip_bfloat16 h = __float2bfloat16(v);
  return *reinterpret_cast<unsigned short*>(&h);
}
__device__ inline unsigned packbf(float a, float b) {
  return (unsigned)f2bf_bits(a) | ((unsigned)f2bf_bits(b) << 16);
}
__device__ inline unsigned fmono(float v) {
  int b = __float_as_int(v);
  return (unsigned)(b ^ ((b >> 31) | 0x80000000));
}
__device__ inline unsigned bn2(unsigned u, float s0, float h0, float s1, float h1) {
  float v0 = fmaxf(bflo(u) * s0 + h0, 0.f);
  float v1 = fmaxf(bfhi(u) * s1 + h1, 0.f);
  return packbf(v0, v1);
}

// ---- DPP compound-key wave64 reduction (round-6: consume at full exec;
// ---- round-12: NO per-block __threadfence in hot kernels — it flushes L2)
template <int CTRL>
__device__ inline void dpp_step_min(unsigned& hi, unsigned& lo) {
  unsigned hs = (unsigned)__builtin_amdgcn_update_dpp((int)hi, (int)hi, CTRL, 0xF, 0xF, false);
  unsigned ls = (unsigned)__builtin_amdgcn_update_dpp((int)lo, (int)lo, CTRL, 0xF, 0xF, false);
  bool take = (hs < hi) || (hs == hi && ls < lo);
  hi = take ? hs : hi; lo = take ? ls : lo;
}
template <int CTRL>
__device__ inline void dpp_step_maxv_minidx(unsigned& hi, unsigned& lo) {
  unsigned hs = (unsigned)__builtin_amdgcn_update_dpp((int)hi, (int)hi, CTRL, 0xF, 0xF, false);
  unsigned ls = (unsigned)__builtin_amdgcn_update_dpp((int)lo, (int)lo, CTRL, 0xF, 0xF, false);
  bool take = (hs > hi) || (hs == hi && ls < lo);
  hi = take ? hs : hi; lo = take ? ls : lo;
}
__device__ inline void dpp_chain_min(unsigned& hi, unsigned& lo) {
  dpp_step_min<0x111>(hi, lo); dpp_step_min<0x112>(hi, lo);
  dpp_step_min<0x114>(hi, lo); dpp_step_min<0x118>(hi, lo);
  dpp_step_min<0x142>(hi, lo); dpp_step_min<0x143>(hi, lo);
}
__device__ inline void dpp_chain_maxv_minidx(unsigned& hi, unsigned& lo) {
  dpp_step_maxv_minidx<0x111>(hi, lo); dpp_step_maxv_minidx<0x112>(hi, lo);
  dpp_step_maxv_minidx<0x114>(hi, lo); dpp_step_maxv_minidx<0x118>(hi, lo);
  dpp_step_maxv_minidx<0x142>(hi, lo); dpp_step_maxv_minidx<0x143>(hi, lo);
}
__device__ inline int dpp_reduce_min_idx(unsigned hi, unsigned lo) {
  dpp_chain_min(hi, lo);
  return __builtin_amdgcn_readlane((int)lo, 63);
}

// ================================================================ MEGA1
__global__ __launch_bounds__(256, 1) void k_mega1(
    const float* __restrict__ x, const float* __restrict__ emb_w1,
    float* __restrict__ fA, double* __restrict__ rsE1, double* __restrict__ rqE1,
    int* __restrict__ fps1, float* __restrict__ nx1,
    int* __restrict__ fps2, float* __restrict__ nx2,
    const float* __restrict__ w11f, __hip_bfloat16* __restrict__ wb11,
    const float* __restrict__ w12f, __hip_bfloat16* __restrict__ wb12,
    const float* __restrict__ w21f, __hip_bfloat16* __restrict__ wb21,
    const float* __restrict__ w22f, __hip_bfloat16* __restrict__ wb22) {
  int blk = blockIdx.x;
  int t = threadIdx.x;
  if (blk < BB) {
    constexpr int PPL = NN / 256;   // 8
    int b = blk; int w = t >> 6; int lane = t & 63;
    __shared__ float4 sxyz[NN];
    __shared__ float4 c4[SS1];
    __shared__ unsigned combH[2][4], combL[2][4];
    float px[PPL], py[PPL], pz[PPL], ds[PPL];
#pragma unroll
    for (int r = 0; r < PPL; r++) {
      int i = r * 256 + t;
      float xx = x[(size_t)(b * 3 + 0) * NN + i];
      float yy = x[(size_t)(b * 3 + 1) * NN + i];
      float zz = x[(size_t)(b * 3 + 2) * NN + i];
      px[r] = xx; py[r] = yy; pz[r] = zz;
      float ox = xx, oy = yy, oz = zz;
      asm volatile("" : "+v"(ox), "+v"(oy), "+v"(oz));  // kill LDS<->reg CSE
      float4 o4 = {ox, oy, oz, 0.f};
      sxyz[i] = o4;
      ds[r] = 1e10f;
    }
    __syncthreads();
    int far = 0; int p = 0;
    for (int it = 0; it < SS1; it++) {
      float4 f4 = sxyz[far];
      float fx = f4.x, fy = f4.y, fz = f4.z;
      if (t == 0) {
        fps1[b * SS1 + it] = far;
        size_t ob = ((size_t)b * SS1 + it) * 3;
        nx1[ob] = fx; nx1[ob + 1] = fy; nx1[ob + 2] = fz;
        c4[it] = f4;
      }
      float mm0 = -1.f, mm1 = -1.f, mm2 = -1.f, mm3 = -1.f;
#pragma unroll
      for (int r = 0; r < PPL; r++) {
        float dx = px[r] - fx, dy = py[r] - fy, dz = pz[r] - fz;
        float d = dx * dx + dy * dy + dz * dz;
        float nd = d < ds[r] ? d : ds[r];
        ds[r] = nd;
        if ((r & 3) == 0) mm0 = nd > mm0 ? nd : mm0;
        else if ((r & 3) == 1) mm1 = nd > mm1 ? nd : mm1;
        else if ((r & 3) == 2) mm2 = nd > mm2 ? nd : mm2;
        else mm3 = nd > mm3 ? nd : mm3;
      }
      float m = fmaxf(fmaxf(mm0, mm1), fmaxf(mm2, mm3));
      int cand[PPL];
#pragma unroll
      for (int r = 0; r < PPL; r++) cand[r] = (ds[r] == m) ? (r * 256 + t) : 0x7fffffff;
#pragma unroll
      for (int st = PPL / 2; st > 0; st >>= 1)
#pragma unroll
        for (int r = 0; r < st; r++) cand[r] = cand[r] < cand[r + st] ? cand[r] : cand[r + st];
      unsigned hi = __float_as_uint(m);
      unsigned lo = (unsigned)cand[0];
      dpp_chain_maxv_minidx(hi, lo);
      unsigned rh = (unsigned)__builtin_amdgcn_readlane((int)hi, 63);  // full exec
      unsigned rl = (unsigned)__builtin_amdgcn_readlane((int)lo, 63);
      if (lane == 0) { combH[p][w] = rh; combL[p][w] = rl; }
      __syncthreads();
      unsigned bh = combH[p][0], bl = combL[p][0];
#pragma unroll
      for (int ww = 1; ww < 4; ww++) {
        unsigned oh = combH[p][ww], ol = combL[p][ww];
        bool take = (oh > bh) || (oh == bh && ol < bl);
        bh = take ? oh : bh; bl = take ? ol : bl;
      }
      far = (int)bl;
      p ^= 1;
    }
    // ---- stage 2: single wave, 512 pts in regs (8/lane), NO barriers.
    __syncthreads();
    if (t >= 64) return;
    float qx[8], qy[8], qz[8], es[8];
#pragma unroll
    for (int r = 0; r < 8; r++) {
      float4 v = c4[r * 64 + t];
      qx[r] = v.x; qy[r] = v.y; qz[r] = v.z; es[r] = 1e10f;
    }
    int far2 = 0;
    for (int it = 0; it < SS2; it++) {
      float4 f4 = c4[far2];
      float fx = f4.x, fy = f4.y, fz = f4.z;
      if (t == 0) {
        fps2[b * SS2 + it] = far2;
        size_t ob = ((size_t)b * SS2 + it) * 3;
        nx2[ob] = fx; nx2[ob + 1] = fy; nx2[ob + 2] = fz;
      }
      float mm0 = -1.f, mm1 = -1.f, mm2 = -1.f, mm3 = -1.f;
#pragma unroll
      for (int r = 0; r < 8; r++) {
        float dx = qx[r] - fx, dy = qy[r] - fy, dz = qz[r] - fz;
        float d = dx * dx + dy * dy + dz * dz;
        float nd = d < es[r] ? d : es[r];
        es[r] = nd;
        if ((r & 3) == 0) mm0 = nd > mm0 ? nd : mm0;
        else if ((r & 3) == 1) mm1 = nd > mm1 ? nd : mm1;
        else if ((r & 3) == 2) mm2 = nd > mm2 ? nd : mm2;
        else mm3 = nd > mm3 ? nd : mm3;
      }
      float m = fmaxf(fmaxf(mm0, mm1), fmaxf(mm2, mm3));
      int cand[8];
#pragma unroll
      for (int r = 0; r < 8; r++) cand[r] = (es[r] == m) ? (r * 64 + t) : 0x7fffffff;
#pragma unroll
      for (int st = 4; st > 0; st >>= 1)
#pragma unroll
        for (int r = 0; r < st; r++) cand[r] = cand[r] < cand[r + st] ? cand[r] : cand[r + st];
      unsigned hi = __float_as_uint(m), lo = (unsigned)cand[0];
      dpp_chain_maxv_minidx(hi, lo);
      far2 = __builtin_amdgcn_readlane((int)lo, 63);
    }
    return;
  }
  blk -= BB;
  if (blk < 8192) {
    __shared__ float ls[64], lq[64];
    if (t < 64) { ls[t] = 0.f; lq[t] = 0.f; }
    __syncthreads();
    int o = t & 63;
    int pt = blk * 4 + (t >> 6);
    int b = pt >> 11, n = pt & (NN - 1);
    float x0 = x[(size_t)(b * 3 + 0) * NN + n];
    float x1 = x[(size_t)(b * 3 + 1) * NN + n];
    float x2 = x[(size_t)(b * 3 + 2) * NN + n];
    float v = x0 * emb_w1[o * 3] + x1 * emb_w1[o * 3 + 1] + x2 * emb_w1[o * 3 + 2];
    fA[(size_t)pt * 64 + o] = v;
    atomicAdd(&ls[o], v);
    atomicAdd(&lq[o], v * v);
    __syncthreads();
    if (t < 64) {
      int rep = blk & 63;
      atomicAdd(&rsE1[(size_t)rep * 64 + t], (double)ls[t]);
      atomicAdd(&rqE1[(size_t)rep * 64 + t], (double)lq[t]);
    }
    return;
  }
  blk -= 8192;
  if (blk < 64) { int i = blk * 256 + t; wb11[i] = __float2bfloat16(w11f[i]); return; }
  blk -= 64;
  if (blk < 64) { int i = blk * 256 + t; wb12[i] = __float2bfloat16(w12f[i]); return; }
  blk -= 64;
  if (blk < 512) { int i = blk * 256 + t; wb21[i] = __float2bfloat16(w21f[i]); return; }
  blk -= 512;
  { int i = blk * 256 + t; wb22[i] = __float2bfloat16(w22f[i]); }
}

// ================================================================ MEGA2
__global__ __launch_bounds__(256) void k_mega2(
    const float* __restrict__ x, const float* __restrict__ nx1, int* __restrict__ knn1,
    const float* __restrict__ nx2, int* __restrict__ knn2,
    const float* __restrict__ fA, const float* __restrict__ sce1,
    const float* __restrict__ she1, const float* __restrict__ w2,
    float* __restrict__ fB, double* __restrict__ rsE2, double* __restrict__ rqE2) {
  int blk = blockIdx.x; int t = threadIdx.x;
  if (blk < 2048) {
    constexpr int PPL = NN / 64;  // 32
    int lane = t & 63;
    int center = blk * 4 + (t >> 6);
    int b = center >> 9;
    float cx = nx1[(size_t)center * 3], cy = nx1[(size_t)center * 3 + 1],
          cz = nx1[(size_t)center * 3 + 2];
    float cn = cx * cx + cy * cy + cz * cz;
    float d2[PPL];
#pragma unroll
    for (int r = 0; r < PPL; r++) {
      int i = r * 64 + lane;
      float xx = x[(size_t)(b * 3 + 0) * NN + i];
      float yy = x[(size_t)(b * 3 + 1) * NN + i];
      float zz = x[(size_t)(b * 3 + 2) * NN + i];
      d2[r] = cn - 2.f * (cx * xx + cy * yy + cz * zz) + (xx * xx + yy * yy + zz * zz);
    }
    for (int kk = 0; kk < KNb; kk++) {
      float a0 = d2[0], a1 = d2[1], a2 = d2[2], a3 = d2[3];
#pragma unroll
      for (int r = 4; r < PPL; r += 4) {
        a0 = fminf(a0, d2[r]); a1 = fminf(a1, d2[r + 1]);
        a2 = fminf(a2, d2[r + 2]); a3 = fminf(a3, d2[r + 3]);
      }
      float m = fminf(fminf(a0, a1), fminf(a2, a3));
      int cand[PPL];
#pragma unroll
      for (int r = 0; r < PPL; r++) cand[r] = (d2[r] == m) ? (r * 64 + lane) : 0x7fffffff;
#pragma unroll
      for (int st = PPL / 2; st > 0; st >>= 1)
#pragma unroll
        for (int r = 0; r < st; r++) cand[r] = cand[r] < cand[r + st] ? cand[r] : cand[r + st];
      int widx = dpp_reduce_min_idx(fmono(m), (unsigned)cand[0]);
      if (lane == 0) knn1[(size_t)center * KNb + kk] = widx;
      int wr = widx >> 6, wl = widx & 63;
#pragma unroll
      for (int r = 0; r < PPL; r++) d2[r] = (r == wr && lane == wl) ? 3.4e38f : d2[r];
    }
    return;
  }
  blk -= 2048;
  if (blk < 1024) {
    constexpr int PPL = SS1 / 64;  // 8
    int lane = t & 63;
    int center = blk * 4 + (t >> 6);
    int b = center >> 8;
    float cx = nx2[(size_t)center * 3], cy = nx2[(size_t)center * 3 + 1],
          cz = nx2[(size_t)center * 3 + 2];
    float cn = cx * cx + cy * cy + cz * cz;
    float d2[PPL];
#pragma unroll
    for (int r = 0; r < PPL; r++) {
      int i = r * 64 + lane;
      size_t pb = ((size_t)b * SS1 + i) * 3;
      float xx = nx1[pb], yy = nx1[pb + 1], zz = nx1[pb + 2];
      d2[r] = cn - 2.f * (cx * xx + cy * yy + cz * zz) + (xx * xx + yy * yy + zz * zz);
    }
    for (int kk = 0; kk < KNb; kk++) {
      float a0 = d2[0], a1 = d2[1], a2 = d2[2], a3 = d2[3];
      a0 = fminf(a0, d2[4]); a1 = fminf(a1, d2[5]);
      a2 = fminf(a2, d2[6]); a3 = fminf(a3, d2[7]);
      float m = fminf(fminf(a0, a1), fminf(a2, a3));
      int cand[PPL];
#pragma unroll
      for (int r = 0; r < PPL; r++) cand[r] = (d2[r] == m) ? (r * 64 + lane) : 0x7fffffff;
#pragma unroll
      for (int st = PPL / 2; st > 0; st >>= 1)
#pragma unroll
        for (int r = 0; r < st; r++) cand[r] = cand[r] < cand[r + st] ? cand[r] : cand[r + st];
      int widx = dpp_reduce_min_idx(fmono(m), (unsigned)cand[0]);
      if (lane == 0) knn2[(size_t)center * KNb + kk] = widx;
      int wr = widx >> 6, wl = widx & 63;
#pragma unroll
      for (int r = 0; r < PPL; r++) d2[r] = (r == wr && lane == wl) ? 3.4e38f : d2[r];
    }
    return;
  }
  blk -= 1024;
  // emb2: 16 points per block
  __shared__ float wT[64][65];
  __shared__ float fs[16][64];
  __shared__ float ss[64], sq[64];
#pragma unroll
  for (int k = 0; k < 16; k++) {
    int idx = k * 256 + t;
    wT[idx & 63][idx >> 6] = w2[idx];
  }
  if (t < 64) { ss[t] = 0.f; sq[t] = 0.f; }
  int pt0 = blk * 16;
#pragma unroll
  for (int it = 0; it < 4; it++) {
    int idx = it * 256 + t;
    int p = idx >> 6, c = idx & 63;
    float v = fA[(size_t)(pt0 + p) * 64 + c];
    v = fmaxf(v * sce1[c] + she1[c], 0.f);
    fs[p][c] = v;
  }
  __syncthreads();
#pragma unroll
  for (int it = 0; it < 4; it++) {
    int idx = it * 256 + t;
    int p = idx >> 6, o = idx & 63;
    float acc = 0.f;
#pragma unroll 8
    for (int c = 0; c < 64; c++) acc += fs[p][c] * wT[c][o];
    fB[(size_t)(pt0 + p) * 64 + o] = acc;
    atomicAdd(&ss[o], acc);
    atomicAdd(&sq[o], acc * acc);
  }
  __syncthreads();
  if (t < 64) {
    int rep = blk & 63;
    atomicAdd(&rsE2[(size_t)rep * 64 + t], (double)ss[t]);
    atomicAdd(&rqE2[(size_t)rep * 64 + t], (double)sq[t]);
  }
}

// ---------------------------------------------------------------- MFMA GEMM
// GA=0: read A from Abuf (bf16), optional BNA transform.
// GA=1: gather A=[rel|cf] inline from fB(fp32)+BN(gsc,gsh), fps/knn (sg1).
// GA=2: gather A=[rel|cf] inline from maxb/minb+BN-select (sg2).
// EPI 0: store bf16 C + fused column stats. EPI 1: group max/min + stats.
template <int K, int EPI, bool BNA, int GA>
__global__ __launch_bounds__(256) void k_mgemm(
    const __hip_bfloat16* __restrict__ A, const __hip_bfloat16* __restrict__ W,
    int N, int Mtiles, const float* __restrict__ bias,
    const float* __restrict__ bnsc, const float* __restrict__ bnsh,
    const float* __restrict__ gsrc0, const float* __restrict__ gsrc1,
    const float* __restrict__ gsc, const float* __restrict__ gsh,
    const int* __restrict__ gfps, const int* __restrict__ gknn,
    __hip_bfloat16* __restrict__ Hout,
    float* __restrict__ maxb, float* __restrict__ minb,
    double* __restrict__ rsum, double* __restrict__ rsq) {
  constexpr int SP = 40;
  constexpr int D = K / 2;  // gather feature dim (GA>0)
  int bm = blockIdx.x % Mtiles; int bn = blockIdx.x / Mtiles;
  int t = threadIdx.x; int w = t >> 6; int lane = t & 63;
  int wm = w & 1, wn = w >> 1; int quad = lane >> 4; int l15 = lane & 15;
  __shared__ short As[128 * SP];
  __shared__ short Ws[128 * SP];
  __shared__ float scs[BNA ? K : 1], shs[BNA ? K : 1];
  __shared__ int nbrs[GA ? 128 : 1];
  __shared__ float cfs[GA ? 4 : 1][GA ? D : 1];
  __shared__ float gscs[GA ? D : 1], gshs[GA ? D : 1];
  __shared__ int bGs[4];
  if constexpr (BNA) {
    for (int i = t; i < K; i += 256) { scs[i] = bnsc[i]; shs[i] = bnsh[i]; }
  }
  if constexpr (GA > 0) {
    constexpr int SDIV = (GA == 1) ? SS1 : SS2;
    constexpr int SRCN = (GA == 1) ? NN : SS1;
    if (t < 128) nbrs[t] = gknn[((size_t)bm * 4 + (t >> 5)) * KNb + (t & 31)];
    for (int i = t; i < D; i += 256) { gscs[i] = gsc[i]; gshs[i] = gsh[i]; }
    if (t < 4) bGs[t] = (bm * 4 + t) / SDIV;
    for (int idx = t; idx < 4 * D; idx += 256) {
      int g = idx / D, c = idx - g * D;
      int cidx = bm * 4 + g;
      int b_ = cidx / SDIV;
      int ctr = gfps[cidx];
      size_t rowb = ((size_t)b_ * SRCN + ctr) * D + c;
      float s = gsc[c];
      float v;
      if constexpr (GA == 1) {
        v = fmaxf(gsrc0[rowb] * s + gsh[c], 0.f);
      } else {
        float sel = s > 0.f ? gsrc0[rowb] : gsrc1[rowb];
        v = fmaxf(sel * s + gsh[c], 0.f);
      }
      cfs[g][c] = v;
    }
  }
  f32x4 acc[4][4];
  f32x4 zero = {0.f, 0.f, 0.f, 0.f};
#pragma unroll
  for (int i = 0; i < 4; i++)
#pragma unroll
    for (int j = 0; j < 4; j++) acc[i][j] = zero;

  int srow = t >> 2, sseg = t & 3;
  const short* Ag = (const short*)A;
  const short* Wg = (const short*)W;
  size_t arow0 = (size_t)bm * 128;
  size_t wrow0 = (size_t)bn * 128;

  for (int k0 = 0; k0 < K; k0 += 32) {
    __syncthreads();
    uint4 a0, a1;
    if constexpr (GA > 0) {
      constexpr int SRCN = (GA == 1) ? NN : SS1;
      int col0 = k0 + sseg * 8;
      auto mk = [&](int row) -> uint4 {
        int g = row >> 5;
        unsigned o[4];
        if (col0 < D) {
          int nb = nbrs[row];
          int b_ = bGs[g];
          size_t base = ((size_t)b_ * SRCN + nb) * D + col0;
          float wv[8];
          if constexpr (GA == 1) {
            float4 v0 = *(const float4*)(gsrc0 + base);
            float4 v1 = *(const float4*)(gsrc0 + base + 4);
            wv[0] = v0.x; wv[1] = v0.y; wv[2] = v0.z; wv[3] = v0.w;
            wv[4] = v1.x; wv[5] = v1.y; wv[6] = v1.z; wv[7] = v1.w;
#pragma unroll
            for (int q = 0; q < 8; q++)
              wv[q] = fmaxf(wv[q] * gscs[col0 + q] + gshs[col0 + q], 0.f);
          } else {
            float4 x0 = *(const float4*)(gsrc0 + base);
            float4 x1 = *(const float4*)(gsrc0 + base + 4);
            float4 n0 = *(const float4*)(gsrc1 + base);
            float4 n1 = *(const float4*)(gsrc1 + base + 4);
            float mx[8] = {x0.x, x0.y, x0.z, x0.w, x1.x, x1.y, x1.z, x1.w};
            float mn[8] = {n0.x, n0.y, n0.z, n0.w, n1.x, n1.y, n1.z, n1.w};
#pragma unroll
            for (int q = 0; q < 8; q++) {
              float s = gscs[col0 + q];
              float sel = s > 0.f ? mx[q] : mn[q];
              wv[q] = fmaxf(sel * s + gshs[col0 + q], 0.f);
            }
          }
#pragma unroll
          for (int q = 0; q < 4; q++)
            o[q] = packbf(wv[2 * q] - cfs[g][col0 + 2 * q],
                          wv[2 * q + 1] - cfs[g][col0 + 2 * q + 1]);
        } else {
          int c2 = col0 - D;
#pragma unroll
          for (int q = 0; q < 4; q++)
            o[q] = packbf(cfs[g][c2 + 2 * q], cfs[g][c2 + 2 * q + 1]);
        }
        uint4 out = {o[0], o[1], o[2], o[3]};
        return out;
      };
      a0 = mk(srow);
      a1 = mk(srow + 64);
    } else {
      a0 = *(const uint4*)(Ag + (arow0 + srow) * K + k0 + sseg * 8);
      a1 = *(const uint4*)(Ag + (arow0 + srow + 64) * K + k0 + sseg * 8);
      if constexpr (BNA) {
        int cb = k0 + sseg * 8;
        float s[8], h[8];
#pragma unroll
        for (int q = 0; q < 8; q++) { s[q] = scs[cb + q]; h[q] = shs[cb + q]; }
        a0.x = bn2(a0.x, s[0], h[0], s[1], h[1]);
        a0.y = bn2(a0.y, s[2], h[2], s[3], h[3]);
        a0.z = bn2(a0.z, s[4], h[4], s[5], h[5]);
        a0.w = bn2(a0.w, s[6], h[6], s[7], h[7]);
        a1.x = bn2(a1.x, s[0], h[0], s[1], h[1]);
        a1.y = bn2(a1.y, s[2], h[2], s[3], h[3]);
        a1.z = bn2(a1.z, s[4], h[4], s[5], h[5]);
        a1.w = bn2(a1.w, s[6], h[6], s[7], h[7]);
      }
    }
    uint4 b0 = *(const uint4*)(Wg + (wrow0 + srow) * K + k0 + sseg * 8);
    uint4 b1 = *(const uint4*)(Wg + (wrow0 + srow + 64) * K + k0 + sseg * 8);
    *(uint4*)(As + srow * SP + sseg * 8) = a0;
    *(uint4*)(As + (srow + 64) * SP + sseg * 8) = a1;
    *(uint4*)(Ws + srow * SP + sseg * 8) = b0;
    *(uint4*)(Ws + (srow + 64) * SP + sseg * 8) = b1;
    __syncthreads();
    bf16x8 af[4], bfr[4];
#pragma unroll
    for (int i = 0; i < 4; i++)
      af[i] = *(const bf16x8*)(As + (wm * 64 + i * 16 + l15) * SP + quad * 8);
#pragma unroll
    for (int j = 0; j < 4; j++)
      bfr[j] = *(const bf16x8*)(Ws + (wn * 64 + j * 16 + l15) * SP + quad * 8);
#pragma unroll
    for (int i = 0; i < 4; i++)
#pragma unroll
      for (int j = 0; j < 4; j++)
        acc[i][j] = __builtin_amdgcn_mfma_f32_16x16x32_bf16(af[i], bfr[j], acc[i][j], 0, 0, 0);
  }

  if constexpr (EPI == 0) {
    int rep = blockIdx.x & 63;
#pragma unroll
    for (int j = 0; j < 4; j++) {
      int col = bn * 128 + wn * 64 + j * 16 + l15;
      float bs = bias[col];
      float su = 0.f, sq = 0.f;
#pragma unroll
      for (int i = 0; i < 4; i++)
#pragma unroll
        for (int r = 0; r < 4; r++) {
          int row = bm * 128 + wm * 64 + i * 16 + quad * 4 + r;
          float v = acc[i][j][r] + bs;
          Hout[(size_t)row * N + col] = __float2bfloat16(v);
          su += v; sq += v * v;
        }
      atomicAdd(&rsum[(size_t)rep * N + col], (double)su);
      atomicAdd(&rsq[(size_t)rep * N + col], (double)sq);
    }
  } else {
    __shared__ float buf[128][33];
    for (int s = 0; s < 4; s++) {
      __syncthreads();
      if (wn == (s >> 1)) {
        int jb = 2 * (s & 1);
#pragma unroll
        for (int jj = 0; jj < 2; jj++) {
          int j = jb + jj;
          int lcol = jj * 16 + l15;
          float bs = bias[bn * 128 + s * 32 + lcol];
#pragma unroll
          for (int i = 0; i < 4; i++)
#pragma unroll
            for (int r = 0; r < 4; r++)
              buf[wm * 64 + i * 16 + quad * 4 + r][lcol] = acc[i][j][r] + bs;
        }
      }
      __syncthreads();
      if (t < 128) {
        int g = t >> 5, c = t & 31;
        float mx = -3.4e38f, mn = 3.4e38f, su = 0.f, sq = 0.f;
#pragma unroll
        for (int r = 0; r < 32; r++) {
          float v = buf[g * 32 + r][c];
          mx = fmaxf(mx, v); mn = fminf(mn, v);
          su += v; sq += v * v;
        }
        int col = bn * 128 + s * 32 + c;
        size_t gidx = (size_t)bm * 4 + g;
        maxb[gidx * N + col] = mx;
        minb[gidx * N + col] = mn;
        int rep = blockIdx.x & 63;
        atomicAdd(&rsum[(size_t)rep * N + col], (double)su);
        atomicAdd(&rsq[(size_t)rep * N + col], (double)sq);
      }
    }
  }
}

// ---------------------------------------------------------------- finalize BN stats
__global__ void k_finalize(const double* __restrict__ rsum, const double* __restrict__ rsq,
                           int O, int rows,
                           const float* __restrict__ gamma, const float* __restrict__ beta,
                           float* __restrict__ scale, float* __restrict__ shift) {
  int o = blockIdx.x * blockDim.x + threadIdx.x;
  if (o >= O) return;
  double s = 0, s2 = 0;
  for (int r = 0; r < 64; r++) { s += rsum[(size_t)r * O + o]; s2 += rsq[(size_t)r * O + o]; }
  double mean = s / rows;
  double var = s2 / rows - mean * mean;
  float sc = gamma[o] * rsqrtf((float)var + EPS_BN);
  scale[o] = sc; shift[o] = beta[o] - (float)mean * sc;
}

// ---------------------------------------------------------------- final output (transposed store)
__global__ void k_final_out(const float* __restrict__ maxb, const float* __restrict__ minb,
                            const float* __restrict__ scale, const float* __restrict__ shift,
                            float* __restrict__ out) {
  int idx = blockIdx.x * blockDim.x + threadIdx.x;
  if (idx >= BB * SS2 * 512) return;
  int o = idx % 512; int si = (idx / 512) % SS2; int b = idx / (512 * SS2);
  float sc = scale[o];
  float sel = sc > 0.f ? maxb[idx] : minb[idx];
  out[((size_t)b * 512 + o) * SS2 + si] = fmaxf(sel * sc + shift[o], 0.f);
}

// ---------------------------------------------------------------- host
extern "C" void kernel_launch(void* const* d_in, const int* in_sizes, int n_in,
                              void* d_out, int out_size, void* d_ws, size_t ws_size,
                              hipStream_t stream) {
  const float* x       = (const float*)d_in[0];
  const float* emb_w1  = (const float*)d_in[1];
  const float* emb_g1  = (const float*)d_in[2];
  const float* emb_b1  = (const float*)d_in[3];
  const float* emb_w2  = (const float*)d_in[4];
  const float* emb_g2  = (const float*)d_in[5];
  const float* emb_b2  = (const float*)d_in[6];
  const float* sg1_w1  = (const float*)d_in[7];
  const float* sg1_cb1 = (const float*)d_in[8];
  const float* sg1_g1  = (const float*)d_in[9];
  const float* sg1_b1  = (const float*)d_in[10];
  const float* sg1_w2  = (const float*)d_in[11];
  const float* sg1_cb2 = (const float*)d_in[12];
  const float* sg1_g2  = (const float*)d_in[13];
  const float* sg1_b2  = (const float*)d_in[14];
  const float* sg2_w1  = (const float*)d_in[15];
  const float* sg2_cb1 = (const float*)d_in[16];
  const float* sg2_g1  = (const float*)d_in[17];
  const float* sg2_b1  = (const float*)d_in[18];
  const float* sg2_w2  = (const float*)d_in[19];
  const float* sg2_cb2 = (const float*)d_in[20];
  const float* sg2_g2  = (const float*)d_in[21];
  const float* sg2_b2  = (const float*)d_in[22];

  char* ws = (char*)d_ws;
  size_t off = 0;
  auto alloc = [&](size_t bytes) -> size_t {
    size_t cur = off; off += (bytes + 255) & ~(size_t)255; return cur;
  };
  float* fA   = (float*)(ws + alloc((size_t)BB * NN * 64 * 4));
  float* fB   = (float*)(ws + alloc((size_t)BB * NN * 64 * 4));
  float* nx1  = (float*)(ws + alloc((size_t)BB * SS1 * 3 * 4));
  float* nx2  = (float*)(ws + alloc((size_t)BB * SS2 * 3 * 4));
  int* fps1   = (int*)(ws + alloc((size_t)BB * SS1 * 4));
  int* fps2   = (int*)(ws + alloc((size_t)BB * SS2 * 4));
  int* knn1   = (int*)(ws + alloc((size_t)BB * SS1 * KNb * 4));
  int* knn2   = (int*)(ws + alloc((size_t)BB * SS2 * KNb * 4));
  float* maxb = (float*)(ws + alloc((size_t)BB * SS2 * 512 * 4));
  float* minb = (float*)(ws + alloc((size_t)BB * SS2 * 512 * 4));
  float* scbuf = (float*)(ws + alloc((size_t)12 * 512 * 4));
  float* sc11 = scbuf + 4 * 512, *sh11 = scbuf + 5 * 512;
  float* sc12 = scbuf + 6 * 512, *sh12 = scbuf + 7 * 512;
  float* sc21 = scbuf + 8 * 512, *sh21 = scbuf + 9 * 512;
  float* sc22 = scbuf + 10 * 512, *sh22 = scbuf + 11 * 512;
  float* sc_e1 = scbuf + 0 * 512, *sh_e1 = scbuf + 1 * 512;
  float* sc_e2 = scbuf + 2 * 512, *sh_e2 = scbuf + 3 * 512;
  size_t statsz = (size_t)12 * 64 * 512 * 8;
  char* statz = ws + alloc(statsz);
  double* st = (double*)statz;
  double* rsA = st + 0 * 64 * 512, *rqA = st + 1 * 64 * 512;
  double* rsB = st + 2 * 64 * 512, *rqB = st + 3 * 64 * 512;
  double* rsC = st + 4 * 64 * 512, *rqC = st + 5 * 64 * 512;
  double* rsD = st + 6 * 64 * 512, *rqD = st + 7 * 64 * 512;
  double* rsE1 = st + 8 * 64 * 512, *rqE1 = st + 9 * 64 * 512;
  double* rsE2 = st + 10 * 64 * 512, *rqE2 = st + 11 * 64 * 512;
  __hip_bfloat16* wb11 = (__hip_bfloat16*)(ws + alloc(128 * 128 * 2));
  __hip_bfloat16* wb12 = (__hip_bfloat16*)(ws + alloc(128 * 128 * 2));
  __hip_bfloat16* wb21 = (__hip_bfloat16*)(ws + alloc(512 * 256 * 2));
  __hip_bfloat16* wb22 = (__hip_bfloat16*)(ws + alloc(512 * 512 * 2));
  __hip_bfloat16* Hbuf = (__hip_bfloat16*)(ws + alloc((size_t)131072 * 512 * 2));  // 128MB

  hipMemsetAsync(statz, 0, statsz, stream);

  const int thr = 256;
  k_mega1<<<9872, 256, 0, stream>>>(x, emb_w1, fA, rsE1, rqE1, fps1, nx1, fps2, nx2,
                                    sg1_w1, wb11, sg1_w2, wb12, sg2_w1, wb21, sg2_w2, wb22);
  k_finalize<<<1, 64, 0, stream>>>(rsE1, rqE1, 64, BB * NN, emb_g1, emb_b1, sc_e1, sh_e1);
  k_mega2<<<5120, 256, 0, stream>>>(x, nx1, knn1, nx2, knn2, fA, sc_e1, sh_e1, emb_w2,
                                    fB, rsE2, rqE2);
  k_finalize<<<1, 64, 0, stream>>>(rsE2, rqE2, 64, BB * NN, emb_g2, emb_b2, sc_e2, sh_e2);

  // ---- SG1: gather fused into GEMM1 (GA=1). M=262144, K=128, N=128
  k_mgemm<128, 0, false, 1><<<2048, 256, 0, stream>>>(
      nullptr, wb11, 128, 2048, sg1_cb1, nullptr, nullptr,
      fB, nullptr, sc_e2, sh_e2, fps1, knn1,
      Hbuf, nullptr, nullptr, rsA, rqA);
  k_finalize<<<1, 128, 0, stream>>>(rsA, rqA, 128, 262144, sg1_g1, sg1_b1, sc11, sh11);
  k_mgemm<128, 1, true, 0><<<2048, 256, 0, stream>>>(
      Hbuf, wb12, 128, 2048, sg1_cb2, sc11, sh11,
      nullptr, nullptr, nullptr, nullptr, nullptr, nullptr,
      nullptr, maxb, minb, rsB, rqB);
  k_finalize<<<1, 128, 0, stream>>>(rsB, rqB, 128, 262144, sg1_g2, sg1_b2, sc12, sh12);

  // ---- SG2: gather fused into GEMM3 (GA=2). M=131072, K=256->512, N=512
  k_mgemm<256, 0, false, 2><<<1024 * 4, 256, 0, stream>>>(
      nullptr, wb21, 512, 1024, sg2_cb1, nullptr, nullptr,
      maxb, minb, sc12, sh12, fps2, knn2,
      Hbuf, nullptr, nullptr, rsC, rqC);
  k_finalize<<<4, 128, 0, stream>>>(rsC, rqC, 512, 131072, sg2_g1, sg2_b1, sc21, sh21);
  k_mgemm<512, 1, true, 0><<<1024 * 4, 256, 0, stream>>>(
      Hbuf, wb22, 512, 1024, sg2_cb2, sc21, sh21,
      nullptr, nullptr, nullptr, nullptr, nullptr, nullptr,
      nullptr, maxb, minb, rsD, rqD);
  k_finalize<<<4, 128, 0, stream>>>(rsD, rqD, 512, 131072, sg2_g2, sg2_b2, sc22, sh22);
  k_final_out<<<(BB * SS2 * 512 + thr - 1) / thr, thr, 0, stream>>>(maxb, minb, sc22, sh22,
                                                                    (float*)d_out);
}